// Round 13
// baseline (571.311 us; speedup 1.0000x reference)
//
#include <hip/hip_runtime.h>
#include <hip/hip_bf16.h>

#define NPTS 4096
#define CC   128
#define KNN  16
#define CNT_PER_GROUP 1048576.0f  // 16 ch * 4096 n * 16 k
#define STAT_STRIDE 1024          // 32 partial slots x [b(2) x g(8) x 2]

typedef __attribute__((ext_vector_type(8))) short bf16x8;
typedef __attribute__((ext_vector_type(8))) unsigned short u16x8;
typedef __attribute__((ext_vector_type(4))) float f32x4;
typedef unsigned short ushort_t;

static __device__ __forceinline__ ushort_t f2bf(float f) {
    __hip_bfloat16 h = __float2bfloat16(f);   // RNE
    ushort_t u; __builtin_memcpy(&u, &h, 2);
    return u;
}
static __device__ __forceinline__ float bf2f(ushort_t u) {
    unsigned v = (unsigned)u << 16;
    float f; __builtin_memcpy(&f, &v, 4);
    return f;
}

// ---------------------------------------------------------------- prep
__global__ void prep_kernel(const float* __restrict__ t11_w, const float* __restrict__ t22_w,
                            const float* __restrict__ t1_w,  const float* __restrict__ t2_w,
                            const float* __restrict__ m1a_w, const float* __restrict__ m1b_w,
                            const float* __restrict__ m2a_w,
                            float* __restrict__ wTt11, float* __restrict__ wTt22,
                            float* __restrict__ wTt1,  float* __restrict__ wTt2,
                            ushort_t* __restrict__ W2m1a, ushort_t* __restrict__ W2m1b,
                            ushort_t* __restrict__ W2m2a, float* __restrict__ stats) {
    int y = blockIdx.y;
    int idx = blockIdx.x * 256 + threadIdx.x;
    if (y == 7) {
        if (idx < 8 * STAT_STRIDE) stats[idx] = 0.0f;
        return;
    }
    if (y < 4) {
        const float* in; float* outp; int Cdim;
        switch (y) {
            case 0: in = t11_w; outp = wTt11; Cdim = 64; break;
            case 1: in = t22_w; outp = wTt22; Cdim = 64; break;
            case 2: in = t1_w;  outp = wTt1;  Cdim = CC; break;
            default: in = t2_w; outp = wTt2;  Cdim = CC; break;
        }
        if (idx < CC * Cdim) {
            int o = idx / Cdim, c = idx % Cdim;
            outp[c * CC + o] = in[idx];
        }
        return;
    }
    const float* in = y == 4 ? m1a_w : y == 5 ? m1b_w : m2a_w;
    ushort_t* outp  = y == 4 ? W2m1a : y == 5 ? W2m1b : W2m2a;
    if (idx < 16384) {
        int j = idx & 7, lane = (idx >> 3) & 63, coT = (idx >> 9) & 7, kb = idx >> 12;
        int k  = kb * 32 + (lane >> 4) * 8 + j;
        int co = coT * 16 + (lane & 15);
        outp[idx] = f2bf(in[co * CC + k]);
    }
}

// ------------------------------------------------- conv1d 64->128, LDS-staged tile GEMM
__global__ __launch_bounds__(256) void conv64_kernel(
        const float* __restrict__ feat1, const float* __restrict__ feat2,
        const float* __restrict__ wTt11, const float* __restrict__ wTt22,
        const float* __restrict__ b11, const float* __restrict__ b22,
        float* __restrict__ f1, float* __restrict__ f2,
        float* __restrict__ g1, float* __restrict__ g2) {
    __shared__ float xs[64][68];
    int y = blockIdx.y;
    const float* x  = (y == 0 || y == 3) ? feat1 : feat2;
    const float* wT = (y == 0 || y == 2) ? wTt11 : wTt22;
    const float* bias = (y == 0 || y == 2) ? b11 : b22;
    float* outp = y == 0 ? f1 : y == 1 ? f2 : y == 2 ? g1 : g2;
    int tid = threadIdx.x;
    int n0 = blockIdx.x * 64;
    int b = n0 >> 12, nloc = n0 & 4095;
    const float* xb = x + (size_t)b * 64 * NPTS + nloc;
    #pragma unroll
    for (int i = 0; i < 16; ++i) {
        int e = tid + 256 * i;
        int ci = e >> 6, nn = e & 63;
        xs[ci][nn] = xb[(size_t)ci * NPTS + nn];
    }
    __syncthreads();
    int co = (tid & 31) * 4;
    int r0 = (tid >> 5) * 8;
    float acc[4][8];
    float4 bv = *(const float4*)&bias[co];
    #pragma unroll
    for (int j = 0; j < 8; ++j) { acc[0][j] = bv.x; acc[1][j] = bv.y; acc[2][j] = bv.z; acc[3][j] = bv.w; }
    for (int ci = 0; ci < 64; ++ci) {
        float4 wv = *(const float4*)&wT[(size_t)ci * CC + co];
        #pragma unroll
        for (int j = 0; j < 8; ++j) {
            float xv = xs[ci][r0 + j];
            acc[0][j] += wv.x * xv;
            acc[1][j] += wv.y * xv;
            acc[2][j] += wv.z * xv;
            acc[3][j] += wv.w * xv;
        }
    }
    #pragma unroll
    for (int j = 0; j < 8; ++j) {
        *(float4*)&outp[(size_t)(n0 + r0 + j) * CC + co] =
            make_float4(acc[0][j], acc[1][j], acc[2][j], acc[3][j]);
    }
}

// ---------------------------------------------------------------- 64-bit shuffles
static __device__ __forceinline__ unsigned long long sxor64(unsigned long long v, int m) {
    unsigned lo = (unsigned)__shfl_xor((int)(unsigned)v, m);
    unsigned hi = (unsigned)__shfl_xor((int)(v >> 32), m);
    return ((unsigned long long)hi << 32) | lo;
}

// ------------------------------------------------- KNN: atomic-append pass 2
__global__ __launch_bounds__(512) void knn_kernel(
        const float* __restrict__ pc1, const float* __restrict__ pc2,
        int* __restrict__ idx12, int* __restrict__ idx21) {
#pragma clang fp contract(off)
    __shared__ float4 pk[NPTS];                           // 64 KB
    __shared__ unsigned long long lst[8][4][63];          // 15.75 KB
    __shared__ int cnt[8][4];                             // 128 B
    int dir = blockIdx.y;
    const float* qs = dir ? pc2 : pc1;
    const float* cs = dir ? pc1 : pc2;
    int* outIdx = dir ? idx21 : idx12;
    int tid = threadIdx.x, lane = tid & 63, wv = tid >> 6;
    int qbase = blockIdx.x * 32;
    int b = qbase >> 12;
    const float* cb = cs + (size_t)b * 3 * NPTS;
    for (int i = tid; i < NPTS; i += 512) {
        float x = cb[i], y = cb[NPTS + i], z = cb[2 * NPTS + i];
        pk[i] = make_float4(x, y, z, x * x + y * y + z * z);  // l2r, no fma
    }
    __syncthreads();
    const float* qb = qs + (size_t)b * 3 * NPTS;
    int q0 = qbase + wv * 4;
    float qx[4], qy[4], qz[4], s1[4], dmin[4], T[4];
    #pragma unroll
    for (int t = 0; t < 4; ++t) {
        int n = (q0 + t) & 4095;
        qx[t] = qb[n]; qy[t] = qb[NPTS + n]; qz[t] = qb[2 * NPTS + n];
        s1[t] = qx[t] * qx[t] + qy[t] * qy[t] + qz[t] * qz[t];
        dmin[t] = 1e30f;
    }
    for (int j = 0; j < 64; ++j) {
        float4 P = pk[j * 64 + lane];
        #pragma unroll
        for (int t = 0; t < 4; ++t) {
            float dt = __builtin_fmaf(P.z, qz[t], __builtin_fmaf(P.y, qy[t], P.x * qx[t]));
            float d2 = (s1[t] + P.w) - 2.0f * dt;
            dmin[t] = fminf(dmin[t], d2);
        }
    }
    #pragma unroll
    for (int t = 0; t < 4; ++t) {
        float sv = dmin[t];
        for (int k = 2; k <= 64; k <<= 1)
            for (int j = k >> 1; j > 0; j >>= 1) {
                float o = __shfl_xor(sv, j);
                bool tmin = (((lane & k) == 0) == ((lane & j) == 0));
                sv = tmin ? fminf(sv, o) : fmaxf(sv, o);
            }
        T[t] = __shfl(sv, 15);
    }
    if (lane < 4) cnt[wv][lane] = 0;
    for (int j = 0; j < 64; ++j) {
        float4 P = pk[j * 64 + lane];
        int m = j * 64 + lane;
        #pragma unroll
        for (int t = 0; t < 4; ++t) {
            float dt = __builtin_fmaf(P.z, qz[t], __builtin_fmaf(P.y, qy[t], P.x * qx[t]));
            float d2 = (s1[t] + P.w) - 2.0f * dt;
            if (d2 <= T[t]) {
                unsigned u = __float_as_uint(d2);
                u ^= (unsigned)(((int)u >> 31) | 0x80000000);
                int pos = atomicAdd(&cnt[wv][t], 1);
                if (pos < 63) lst[wv][t][pos] = ((unsigned long long)u << 32) | (unsigned)m;
            }
        }
    }
    #pragma unroll
    for (int t = 0; t < 4; ++t) {
        int nT = cnt[wv][t]; if (nT > 63) nT = 63;
        unsigned long long key = (lane < nT) ? lst[wv][t][lane] : ~0ULL;
        for (int k = 2; k <= 64; k <<= 1)
            for (int j = k >> 1; j > 0; j >>= 1) {
                unsigned long long o = sxor64(key, j);
                bool tmin = (((lane & k) == 0) == ((lane & j) == 0));
                unsigned long long mn = key < o ? key : o;
                unsigned long long mx = key < o ? o : key;
                key = tmin ? mn : mx;
            }
        if (lane < KNN) outIdx[(size_t)(q0 + t) * KNN + lane] = (int)(unsigned)(key & 0xFFFFFFFFULL);
    }
}

// ------------------------------------------------- h0 (dual: cross1 / cross2 by blockIdx.y)
__global__ void h0_kernel(const float* p1f_1, const float* p2f_1,
                          const float* p1f_2, const float* p2f_2,
                          const float* __restrict__ pc1, const float* __restrict__ pc2,
                          const int* idx_1, const int* idx_2,
                          const float* __restrict__ pos_w, const float* __restrict__ pos_b,
                          ushort_t* buf_1, ushort_t* buf_2,
                          float* stats_1, float* stats_2) {
    __shared__ float redS[128], redQ[128];
    int y = blockIdx.y;
    const float* p1f = y ? p1f_2 : p1f_1;
    const float* p2f = y ? p2f_2 : p2f_1;
    const float* pcA = y ? pc2 : pc1;
    const float* pcB = y ? pc1 : pc2;
    const int* idx = y ? idx_2 : idx_1;
    ushort_t* buf = y ? buf_2 : buf_1;
    float* stats_out = y ? stats_2 : stats_1;
    int p = blockIdx.x;                    // b*N + n
    int b = p >> 12, n = p & 4095;
    int c = threadIdx.x;
    float pw0 = pos_w[c * 3], pw1 = pos_w[c * 3 + 1], pw2 = pos_w[c * 3 + 2];
    float pb = pos_b[c];
    float p1v = p1f[(size_t)p * CC + c];
    const float* pa = pcA + (size_t)b * 3 * NPTS;
    const float* pc = pcB + (size_t)b * 3 * NPTS;
    float qx = pa[n], qy = pa[NPTS + n], qz = pa[2 * NPTS + n];
    float S = 0.f, Q = 0.f;
    for (int k = 0; k < KNN; ++k) {
        int m = idx[(size_t)p * KNN + k];
        float dx = pc[m] - qx;
        float dy = pc[NPTS + m] - qy;
        float dz = pc[2 * NPTS + m] - qz;
        float pos = pw0 * dx + pw1 * dy + pw2 * dz + pb;
        float v = p2f[((size_t)b * NPTS + m) * CC + c] + p1v + pos;
        buf[((size_t)p * KNN + k) * CC + c] = f2bf(v);
        S += v; Q += v * v;
    }
    redS[c] = S; redQ[c] = Q;
    __syncthreads();
    if (c < 8) {
        float SS = 0.f, QQ = 0.f;
        for (int i = 0; i < 16; ++i) { SS += redS[c * 16 + i]; QQ += redQ[c * 16 + i]; }
        int s = blockIdx.x & 31;
        atomicAdd(&stats_out[s * 32 + (b * 8 + c) * 2],     SS);
        atomicAdd(&stats_out[s * 32 + (b * 8 + c) * 2 + 1], QQ);
    }
}

// ------------------------------------------------- convgn v3 (dual): barrier-light.
// A-fragments loaded DIRECTLY from global (u16x8, aggregate-coalesced), GN+lrelu in
// registers; per-wave output slab (no barrier); per-wave stats atomics.
__global__ __launch_bounds__(256) void convgn_kernel(
        const ushort_t* xbuf_1, const ushort_t* xbuf_2,
        const float* stats_in_1, const float* stats_in_2,
        const float* __restrict__ gam, const float* __restrict__ bet,
        const ushort_t* __restrict__ W2, const float* __restrict__ bias,
        ushort_t* ybuf_1, ushort_t* ybuf_2,
        float* stats_out_1, float* stats_out_2) {
    __shared__ ushort_t xt[64 * 136];      // per-wave 16-row output slabs
    __shared__ float sc[CC], sh[CC];
    int y = blockIdx.y;
    const ushort_t* xbuf = y ? xbuf_2 : xbuf_1;
    const float* stats_in = y ? stats_in_2 : stats_in_1;
    ushort_t* ybuf = y ? ybuf_2 : ybuf_1;
    float* stats_out = y ? stats_out_2 : stats_out_1;
    int tid = threadIdx.x;
    int s0 = blockIdx.x * 64;
    int b = s0 >> 16;
    if (tid < CC) {
        int g = tid >> 4;
        float S = 0.f, Q = 0.f;
        for (int s = 0; s < 32; ++s) {
            S += stats_in[s * 32 + (b * 8 + g) * 2];
            Q += stats_in[s * 32 + (b * 8 + g) * 2 + 1];
        }
        float mu = S / CNT_PER_GROUP;
        float var = Q / CNT_PER_GROUP - mu * mu;
        float rs = rsqrtf(var + 1e-5f);
        float scale = gam[tid] * rs;
        sc[tid] = scale;
        sh[tid] = bet[tid] - mu * scale;
    }
    __syncthreads();                       // the only block barrier
    int lane = tid & 63, wv = tid >> 6;
    int r0 = wv * 16;
    int quad = lane >> 4, r = lane & 15;
    // A-fragment loads straight from global: lane covers rows s0+r0+r, k = kb*32+quad*8..+7
    const ushort_t* xrow = xbuf + (size_t)(s0 + r0 + r) * CC + quad * 8;
    f32x4 acc[8];
    #pragma unroll
    for (int t = 0; t < 8; ++t) acc[t] = (f32x4){0.f, 0.f, 0.f, 0.f};
    #pragma unroll
    for (int kb = 0; kb < 4; ++kb) {
        u16x8 raw = *(const u16x8*)&xrow[kb * 32];
        int k0 = kb * 32 + quad * 8;
        bf16x8 a;
        #pragma unroll
        for (int e = 0; e < 8; ++e) {
            float v = bf2f(raw[e]) * sc[k0 + e] + sh[k0 + e];
            v = v >= 0.f ? v : 0.1f * v;
            a[e] = (short)f2bf(v);
        }
        const ushort_t* wb = W2 + (size_t)kb * 4096 + lane * 8;
        #pragma unroll
        for (int t = 0; t < 8; ++t) {
            bf16x8 bf = *(const bf16x8*)&wb[t * 512];
            acc[t] = __builtin_amdgcn_mfma_f32_16x16x32_bf16(a, bf, acc[t], 0, 0, 0);
        }
    }
    // epilogue: bias + per-wave stats atomics; stage bf16 into wave-private slab rows
    #pragma unroll
    for (int t = 0; t < 8; ++t) {
        int co = t * 16 + r;
        float bv = bias[co];
        float S = 0.f, Q = 0.f;
        #pragma unroll
        for (int reg = 0; reg < 4; ++reg) {
            int rl = r0 + quad * 4 + reg;
            float yv = acc[t][reg] + bv;
            xt[rl * 136 + co] = f2bf(yv);
            S += yv; Q += yv * yv;
        }
        #pragma unroll
        for (int off = 1; off < 64; off <<= 1) {
            S += __shfl_xor(S, off);
            Q += __shfl_xor(Q, off);
        }
        if (lane == 0) {
            int s = (blockIdx.x * 4 + wv) & 31;
            atomicAdd(&stats_out[s * 32 + (b * 8 + t) * 2],     S);
            atomicAdd(&stats_out[s * 32 + (b * 8 + t) * 2 + 1], Q);
        }
    }
    // wave-private slab -> coalesced 16B global stores (no barrier: own rows only)
    #pragma unroll
    for (int i = 0; i < 4; ++i) {
        int chunk = i * 64 + lane;             // row(4b) x c8(4b) within wave tile
        int rl = r0 + (chunk >> 4);
        int c8 = (chunk & 15) * 8;
        u16x8 v = *(const u16x8*)&xt[rl * 136 + c8];
        *(u16x8*)&ybuf[(size_t)(s0 + rl) * CC + c8] = v;
    }
}

// ------------------------------------------------- maxpool (cross3 tail), n-run writes
__global__ __launch_bounds__(256) void maxpool_kernel(
        const ushort_t* __restrict__ ybuf, const float* __restrict__ stats,
        const float* __restrict__ gam, const float* __restrict__ bet,
        float* __restrict__ outb) {
    int p0 = blockIdx.x * 16;
    int b = p0 >> 12, n0 = p0 & 4095;
    int tid = threadIdx.x;
    int c = tid & 127, half = tid >> 7;
    int g = c >> 4;
    float S = 0.f, Q = 0.f;
    for (int s = 0; s < 32; ++s) {
        S += stats[s * 32 + (b * 8 + g) * 2];
        Q += stats[s * 32 + (b * 8 + g) * 2 + 1];
    }
    float mu = S / CNT_PER_GROUP;
    float var = Q / CNT_PER_GROUP - mu * mu;
    float rs = rsqrtf(var + 1e-5f);
    float scale = gam[c] * rs;
    float shift = bet[c] - mu * scale;
    float* orow = outb + ((size_t)b * CC + c) * NPTS + n0 + half * 8;
    #pragma unroll
    for (int j = 0; j < 8; ++j) {
        int nl = half * 8 + j;
        float mx = -INFINITY;
        for (int k = 0; k < KNN; ++k) {
            float v = bf2f(ybuf[((size_t)(p0 + nl) * KNN + k) * CC + c]) * scale + shift;
            v = v >= 0.f ? v : 0.1f * v;
            mx = fmaxf(mx, v);
        }
        orow[j] = mx;
    }
}

// ------------------------------------------------- fused maxpool + conv (dual)
__global__ __launch_bounds__(256) void maxconv_kernel(
        const ushort_t* ybuf_1, const ushort_t* ybuf_2,
        const float* stats_1, const float* stats_2,
        const float* __restrict__ gam, const float* __restrict__ bet,
        const float* wT_1, const float* wT_2,
        const float* bias_1, const float* bias_2,
        float* outf_1, float* outf_2,
        float* __restrict__ outb) {
    __shared__ float mxs[16][CC + 4];
    int y = blockIdx.y;
    const ushort_t* ybuf = y ? ybuf_2 : ybuf_1;
    const float* stats = y ? stats_2 : stats_1;
    const float* wT = y ? wT_2 : wT_1;
    const float* bias = y ? bias_2 : bias_1;
    float* outf = y ? outf_2 : outf_1;
    float* ob = outb + (size_t)y * 2 * NPTS * CC;
    int p0 = blockIdx.x * 16;
    int b = p0 >> 12, n0 = p0 & 4095;
    int tid = threadIdx.x;
    int c = tid & 127, half = tid >> 7;
    int g = c >> 4;
    float S = 0.f, Q = 0.f;
    for (int s = 0; s < 32; ++s) {
        S += stats[s * 32 + (b * 8 + g) * 2];
        Q += stats[s * 32 + (b * 8 + g) * 2 + 1];
    }
    float mu = S / CNT_PER_GROUP;
    float var = Q / CNT_PER_GROUP - mu * mu;
    float rs = rsqrtf(var + 1e-5f);
    float scale = gam[c] * rs;
    float shift = bet[c] - mu * scale;
    #pragma unroll
    for (int j = 0; j < 8; ++j) {
        int nl = half * 8 + j;
        float mx = -INFINITY;
        for (int k = 0; k < KNN; ++k) {
            float v = bf2f(ybuf[((size_t)(p0 + nl) * KNN + k) * CC + c]) * scale + shift;
            v = v >= 0.f ? v : 0.1f * v;
            mx = fmaxf(mx, v);
        }
        mxs[nl][c] = mx;
    }
    __syncthreads();
    float acc[8];
    float bv = bias[c];
    #pragma unroll
    for (int j = 0; j < 8; ++j) acc[j] = bv;
    for (int ci = 0; ci < CC; ++ci) {
        float wv = wT[(size_t)ci * CC + c];
        #pragma unroll
        for (int j = 0; j < 8; ++j)
            acc[j] += wv * mxs[half * 8 + j][ci];
    }
    #pragma unroll
    for (int j = 0; j < 8; ++j)
        outf[(size_t)(p0 + half * 8 + j) * CC + c] = acc[j];
    float* orow = ob + ((size_t)b * CC + c) * NPTS + n0 + half * 8;
    #pragma unroll
    for (int j = 0; j < 8; ++j) orow[j] = acc[j];
}

extern "C" void kernel_launch(void* const* d_in, const int* in_sizes, int n_in,
                              void* d_out, int out_size, void* d_ws, size_t ws_size,
                              hipStream_t stream) {
    (void)in_sizes; (void)n_in; (void)out_size; (void)ws_size;
    const float* pc1    = (const float*)d_in[0];
    const float* pc2    = (const float*)d_in[1];
    const float* feat1  = (const float*)d_in[2];
    const float* feat2  = (const float*)d_in[3];
    const float* t11_w  = (const float*)d_in[4];
    const float* t11_b  = (const float*)d_in[5];
    const float* t22_w  = (const float*)d_in[6];
    const float* t22_b  = (const float*)d_in[7];
    const float* pos1_w = (const float*)d_in[8];
    const float* pos1_b = (const float*)d_in[9];
    const float* gn1_g  = (const float*)d_in[10];
    const float* gn1_b  = (const float*)d_in[11];
    const float* m1a_w  = (const float*)d_in[12];
    const float* m1a_b  = (const float*)d_in[13];
    const float* m1a_g  = (const float*)d_in[14];
    const float* m1a_be = (const float*)d_in[15];
    const float* m1b_w  = (const float*)d_in[16];
    const float* m1b_b  = (const float*)d_in[17];
    const float* m1b_g  = (const float*)d_in[18];
    const float* m1b_be = (const float*)d_in[19];
    const float* t1_w   = (const float*)d_in[20];
    const float* t1_b   = (const float*)d_in[21];
    const float* t2_w   = (const float*)d_in[22];
    const float* t2_b   = (const float*)d_in[23];
    const float* pos2_w = (const float*)d_in[24];
    const float* pos2_b = (const float*)d_in[25];
    const float* gn2_g  = (const float*)d_in[26];
    const float* gn2_b  = (const float*)d_in[27];
    const float* m2a_w  = (const float*)d_in[28];
    const float* m2a_b  = (const float*)d_in[29];
    const float* m2a_g  = (const float*)d_in[30];
    const float* m2a_be = (const float*)d_in[31];

    float* out = (float*)d_out;
    const size_t PN = 2 * NPTS;              // 8192 points
    const size_t PT = PN * CC;               // 1,048,576 elements per point-tensor
    float* ws   = (float*)d_ws;
    float* f1   = ws;
    float* f2   = f1 + PT;
    float* g1   = f2 + PT;
    float* g2   = g1 + PT;
    float* f1n  = g2 + PT;
    float* f2n  = f1n + PT;
    int*   idx12 = (int*)(f2n + PT);
    int*   idx21 = idx12 + PN * KNN;
    float* stats = (float*)(idx21 + PN * KNN);     // 8 stages * 1024
    float* wTt11 = stats + 8 * STAT_STRIDE;
    float* wTt22 = wTt11 + 64 * CC;
    float* wTt1  = wTt22 + 64 * CC;
    float* wTt2  = wTt1 + CC * CC;
    ushort_t* W2m1a = (ushort_t*)(wTt2 + CC * CC);
    ushort_t* W2m1b = W2m1a + 16384;
    ushort_t* W2m2a = W2m1b + 16384;
    ushort_t* bufX1 = W2m2a + 16384;               // bf16 [PN*KNN*CC] each
    ushort_t* bufY1 = bufX1 + (size_t)PN * KNN * CC;
    ushort_t* bufX2 = bufY1 + (size_t)PN * KNN * CC;
    ushort_t* bufY2 = bufX2 + (size_t)PN * KNN * CC;

    prep_kernel<<<dim3(64, 8), 256, 0, stream>>>(
        t11_w, t22_w, t1_w, t2_w, m1a_w, m1b_w, m2a_w,
        wTt11, wTt22, wTt1, wTt2, W2m1a, W2m1b, W2m2a, stats);

    conv64_kernel<<<dim3(PN / 64, 4), 256, 0, stream>>>(
        feat1, feat2, wTt11, wTt22, t11_b, t22_b, f1, f2, g1, g2);
    knn_kernel<<<dim3(PN / 32, 2), 512, 0, stream>>>(pc1, pc2, idx12, idx21);

    float* st0 = stats;
    // ---- cross1 + cross2 merged (independent pipelines, blockIdx.y selects)
    h0_kernel<<<dim3(PN, 2), 128, 0, stream>>>(
        f1, f2, g1, g2, pc1, pc2, idx12, idx21, pos1_w, pos1_b,
        bufX1, bufX2, st0 + 0 * STAT_STRIDE, st0 + 3 * STAT_STRIDE);
    convgn_kernel<<<dim3(2048, 2), 256, 0, stream>>>(
        bufX1, bufX2, st0 + 0 * STAT_STRIDE, st0 + 3 * STAT_STRIDE,
        gn1_g, gn1_b, W2m1a, m1a_b,
        bufY1, bufY2, st0 + 1 * STAT_STRIDE, st0 + 4 * STAT_STRIDE);
    convgn_kernel<<<dim3(2048, 2), 256, 0, stream>>>(
        bufY1, bufY2, st0 + 1 * STAT_STRIDE, st0 + 4 * STAT_STRIDE,
        m1a_g, m1a_be, W2m1b, m1b_b,
        bufX1, bufX2, st0 + 2 * STAT_STRIDE, st0 + 5 * STAT_STRIDE);
    maxconv_kernel<<<dim3(PN / 16, 2), 256, 0, stream>>>(
        bufX1, bufX2, st0 + 2 * STAT_STRIDE, st0 + 5 * STAT_STRIDE,
        m1b_g, m1b_be, wTt1, wTt2, t1_b, t2_b, f1n, f2n, out);

    // ---- cross3: (pc1, pc2, feat1_new, feat2_new) -> feat1_final
    h0_kernel<<<dim3(PN, 1), 128, 0, stream>>>(
        f1n, f2n, f1n, f2n, pc1, pc2, idx12, idx12, pos2_w, pos2_b,
        bufX1, bufX1, st0 + 6 * STAT_STRIDE, st0 + 6 * STAT_STRIDE);
    convgn_kernel<<<dim3(2048, 1), 256, 0, stream>>>(
        bufX1, bufX1, st0 + 6 * STAT_STRIDE, st0 + 6 * STAT_STRIDE,
        gn2_g, gn2_b, W2m2a, m2a_b,
        bufY1, bufY1, st0 + 7 * STAT_STRIDE, st0 + 7 * STAT_STRIDE);
    maxpool_kernel<<<PN / 16, 256, 0, stream>>>(
        bufY1, st0 + 7 * STAT_STRIDE, m2a_g, m2a_be, out + 2 * PT);
}

// Round 14
// 553.153 us; speedup vs baseline: 1.0328x; 1.0328x over previous
//
#include <hip/hip_runtime.h>
#include <hip/hip_bf16.h>

#define NPTS 4096
#define CC   128
#define KNN  16
#define CNT_PER_GROUP 1048576.0f  // 16 ch * 4096 n * 16 k
#define STAT_STRIDE 1024          // 32 partial slots x [b(2) x g(8) x 2]

typedef __attribute__((ext_vector_type(8))) short bf16x8;
typedef __attribute__((ext_vector_type(8))) unsigned short u16x8;
typedef __attribute__((ext_vector_type(4))) float f32x4;
typedef unsigned short ushort_t;

static __device__ __forceinline__ ushort_t f2bf(float f) {
    __hip_bfloat16 h = __float2bfloat16(f);   // RNE
    ushort_t u; __builtin_memcpy(&u, &h, 2);
    return u;
}
static __device__ __forceinline__ float bf2f(ushort_t u) {
    unsigned v = (unsigned)u << 16;
    float f; __builtin_memcpy(&f, &v, 4);
    return f;
}

// ---------------------------------------------------------------- prep
__global__ void prep_kernel(const float* __restrict__ t11_w, const float* __restrict__ t22_w,
                            const float* __restrict__ t1_w,  const float* __restrict__ t2_w,
                            const float* __restrict__ m1a_w, const float* __restrict__ m1b_w,
                            const float* __restrict__ m2a_w,
                            float* __restrict__ wTt11, float* __restrict__ wTt22,
                            float* __restrict__ wTt1,  float* __restrict__ wTt2,
                            ushort_t* __restrict__ W2m1a, ushort_t* __restrict__ W2m1b,
                            ushort_t* __restrict__ W2m2a, float* __restrict__ stats) {
    int y = blockIdx.y;
    int idx = blockIdx.x * 256 + threadIdx.x;
    if (y == 7) {
        if (idx < 8 * STAT_STRIDE) stats[idx] = 0.0f;
        return;
    }
    if (y < 4) {
        const float* in; float* outp; int Cdim;
        switch (y) {
            case 0: in = t11_w; outp = wTt11; Cdim = 64; break;
            case 1: in = t22_w; outp = wTt22; Cdim = 64; break;
            case 2: in = t1_w;  outp = wTt1;  Cdim = CC; break;
            default: in = t2_w; outp = wTt2;  Cdim = CC; break;
        }
        if (idx < CC * Cdim) {
            int o = idx / Cdim, c = idx % Cdim;
            outp[c * CC + o] = in[idx];
        }
        return;
    }
    const float* in = y == 4 ? m1a_w : y == 5 ? m1b_w : m2a_w;
    ushort_t* outp  = y == 4 ? W2m1a : y == 5 ? W2m1b : W2m2a;
    if (idx < 16384) {
        int j = idx & 7, lane = (idx >> 3) & 63, coT = (idx >> 9) & 7, kb = idx >> 12;
        int k  = kb * 32 + (lane >> 4) * 8 + j;
        int co = coT * 16 + (lane & 15);
        outp[idx] = f2bf(in[co * CC + k]);
    }
}

// ------------------------------------------------- conv1d 64->128, LDS-staged tile GEMM
__global__ __launch_bounds__(256) void conv64_kernel(
        const float* __restrict__ feat1, const float* __restrict__ feat2,
        const float* __restrict__ wTt11, const float* __restrict__ wTt22,
        const float* __restrict__ b11, const float* __restrict__ b22,
        float* __restrict__ f1, float* __restrict__ f2,
        float* __restrict__ g1, float* __restrict__ g2) {
    __shared__ float xs[64][68];
    int y = blockIdx.y;
    const float* x  = (y == 0 || y == 3) ? feat1 : feat2;
    const float* wT = (y == 0 || y == 2) ? wTt11 : wTt22;
    const float* bias = (y == 0 || y == 2) ? b11 : b22;
    float* outp = y == 0 ? f1 : y == 1 ? f2 : y == 2 ? g1 : g2;
    int tid = threadIdx.x;
    int n0 = blockIdx.x * 64;
    int b = n0 >> 12, nloc = n0 & 4095;
    const float* xb = x + (size_t)b * 64 * NPTS + nloc;
    #pragma unroll
    for (int i = 0; i < 16; ++i) {
        int e = tid + 256 * i;
        int ci = e >> 6, nn = e & 63;
        xs[ci][nn] = xb[(size_t)ci * NPTS + nn];
    }
    __syncthreads();
    int co = (tid & 31) * 4;
    int r0 = (tid >> 5) * 8;
    float acc[4][8];
    float4 bv = *(const float4*)&bias[co];
    #pragma unroll
    for (int j = 0; j < 8; ++j) { acc[0][j] = bv.x; acc[1][j] = bv.y; acc[2][j] = bv.z; acc[3][j] = bv.w; }
    for (int ci = 0; ci < 64; ++ci) {
        float4 wv = *(const float4*)&wT[(size_t)ci * CC + co];
        #pragma unroll
        for (int j = 0; j < 8; ++j) {
            float xv = xs[ci][r0 + j];
            acc[0][j] += wv.x * xv;
            acc[1][j] += wv.y * xv;
            acc[2][j] += wv.z * xv;
            acc[3][j] += wv.w * xv;
        }
    }
    #pragma unroll
    for (int j = 0; j < 8; ++j) {
        *(float4*)&outp[(size_t)(n0 + r0 + j) * CC + co] =
            make_float4(acc[0][j], acc[1][j], acc[2][j], acc[3][j]);
    }
}

// ---------------------------------------------------------------- 64-bit shuffles
static __device__ __forceinline__ unsigned long long sxor64(unsigned long long v, int m) {
    unsigned lo = (unsigned)__shfl_xor((int)(unsigned)v, m);
    unsigned hi = (unsigned)__shfl_xor((int)(v >> 32), m);
    return ((unsigned long long)hi << 32) | lo;
}

// ------------------------------------------------- KNN: atomic-append pass 2
__global__ __launch_bounds__(512) void knn_kernel(
        const float* __restrict__ pc1, const float* __restrict__ pc2,
        int* __restrict__ idx12, int* __restrict__ idx21) {
#pragma clang fp contract(off)
    __shared__ float4 pk[NPTS];                           // 64 KB
    __shared__ unsigned long long lst[8][4][63];          // 15.75 KB
    __shared__ int cnt[8][4];                             // 128 B
    int dir = blockIdx.y;
    const float* qs = dir ? pc2 : pc1;
    const float* cs = dir ? pc1 : pc2;
    int* outIdx = dir ? idx21 : idx12;
    int tid = threadIdx.x, lane = tid & 63, wv = tid >> 6;
    int qbase = blockIdx.x * 32;
    int b = qbase >> 12;
    const float* cb = cs + (size_t)b * 3 * NPTS;
    for (int i = tid; i < NPTS; i += 512) {
        float x = cb[i], y = cb[NPTS + i], z = cb[2 * NPTS + i];
        pk[i] = make_float4(x, y, z, x * x + y * y + z * z);  // l2r, no fma
    }
    __syncthreads();
    const float* qb = qs + (size_t)b * 3 * NPTS;
    int q0 = qbase + wv * 4;
    float qx[4], qy[4], qz[4], s1[4], dmin[4], T[4];
    #pragma unroll
    for (int t = 0; t < 4; ++t) {
        int n = (q0 + t) & 4095;
        qx[t] = qb[n]; qy[t] = qb[NPTS + n]; qz[t] = qb[2 * NPTS + n];
        s1[t] = qx[t] * qx[t] + qy[t] * qy[t] + qz[t] * qz[t];
        dmin[t] = 1e30f;
    }
    for (int j = 0; j < 64; ++j) {
        float4 P = pk[j * 64 + lane];
        #pragma unroll
        for (int t = 0; t < 4; ++t) {
            float dt = __builtin_fmaf(P.z, qz[t], __builtin_fmaf(P.y, qy[t], P.x * qx[t]));
            float d2 = (s1[t] + P.w) - 2.0f * dt;
            dmin[t] = fminf(dmin[t], d2);
        }
    }
    #pragma unroll
    for (int t = 0; t < 4; ++t) {
        float sv = dmin[t];
        for (int k = 2; k <= 64; k <<= 1)
            for (int j = k >> 1; j > 0; j >>= 1) {
                float o = __shfl_xor(sv, j);
                bool tmin = (((lane & k) == 0) == ((lane & j) == 0));
                sv = tmin ? fminf(sv, o) : fmaxf(sv, o);
            }
        T[t] = __shfl(sv, 15);
    }
    if (lane < 4) cnt[wv][lane] = 0;
    for (int j = 0; j < 64; ++j) {
        float4 P = pk[j * 64 + lane];
        int m = j * 64 + lane;
        #pragma unroll
        for (int t = 0; t < 4; ++t) {
            float dt = __builtin_fmaf(P.z, qz[t], __builtin_fmaf(P.y, qy[t], P.x * qx[t]));
            float d2 = (s1[t] + P.w) - 2.0f * dt;
            if (d2 <= T[t]) {
                unsigned u = __float_as_uint(d2);
                u ^= (unsigned)(((int)u >> 31) | 0x80000000);
                int pos = atomicAdd(&cnt[wv][t], 1);
                if (pos < 63) lst[wv][t][pos] = ((unsigned long long)u << 32) | (unsigned)m;
            }
        }
    }
    #pragma unroll
    for (int t = 0; t < 4; ++t) {
        int nT = cnt[wv][t]; if (nT > 63) nT = 63;
        unsigned long long key = (lane < nT) ? lst[wv][t][lane] : ~0ULL;
        for (int k = 2; k <= 64; k <<= 1)
            for (int j = k >> 1; j > 0; j >>= 1) {
                unsigned long long o = sxor64(key, j);
                bool tmin = (((lane & k) == 0) == ((lane & j) == 0));
                unsigned long long mn = key < o ? key : o;
                unsigned long long mx = key < o ? o : key;
                key = tmin ? mn : mx;
            }
        if (lane < KNN) outIdx[(size_t)(q0 + t) * KNN + lane] = (int)(unsigned)(key & 0xFFFFFFFFULL);
    }
}

// ------------------------------------------------- h0 (dual: cross1 / cross2 by blockIdx.y)
__global__ void h0_kernel(const float* p1f_1, const float* p2f_1,
                          const float* p1f_2, const float* p2f_2,
                          const float* __restrict__ pc1, const float* __restrict__ pc2,
                          const int* idx_1, const int* idx_2,
                          const float* __restrict__ pos_w, const float* __restrict__ pos_b,
                          ushort_t* buf_1, ushort_t* buf_2,
                          float* stats_1, float* stats_2) {
    __shared__ float redS[128], redQ[128];
    int y = blockIdx.y;
    const float* p1f = y ? p1f_2 : p1f_1;
    const float* p2f = y ? p2f_2 : p2f_1;
    const float* pcA = y ? pc2 : pc1;
    const float* pcB = y ? pc1 : pc2;
    const int* idx = y ? idx_2 : idx_1;
    ushort_t* buf = y ? buf_2 : buf_1;
    float* stats_out = y ? stats_2 : stats_1;
    int p = blockIdx.x;                    // b*N + n
    int b = p >> 12, n = p & 4095;
    int c = threadIdx.x;
    float pw0 = pos_w[c * 3], pw1 = pos_w[c * 3 + 1], pw2 = pos_w[c * 3 + 2];
    float pb = pos_b[c];
    float p1v = p1f[(size_t)p * CC + c];
    const float* pa = pcA + (size_t)b * 3 * NPTS;
    const float* pc = pcB + (size_t)b * 3 * NPTS;
    float qx = pa[n], qy = pa[NPTS + n], qz = pa[2 * NPTS + n];
    float S = 0.f, Q = 0.f;
    for (int k = 0; k < KNN; ++k) {
        int m = idx[(size_t)p * KNN + k];
        float dx = pc[m] - qx;
        float dy = pc[NPTS + m] - qy;
        float dz = pc[2 * NPTS + m] - qz;
        float pos = pw0 * dx + pw1 * dy + pw2 * dz + pb;
        float v = p2f[((size_t)b * NPTS + m) * CC + c] + p1v + pos;
        buf[((size_t)p * KNN + k) * CC + c] = f2bf(v);
        S += v; Q += v * v;
    }
    redS[c] = S; redQ[c] = Q;
    __syncthreads();
    if (c < 8) {
        float SS = 0.f, QQ = 0.f;
        for (int i = 0; i < 16; ++i) { SS += redS[c * 16 + i]; QQ += redQ[c * 16 + i]; }
        int s = blockIdx.x & 31;
        atomicAdd(&stats_out[s * 32 + (b * 8 + c) * 2],     SS);
        atomicAdd(&stats_out[s * 32 + (b * 8 + c) * 2 + 1], QQ);
    }
}

// ------------------------------------------------- convgn v4 (dual): round-12 structure
// (cooperative LDS staging for MLP burst + MFMA from LDS + wave-private output slab),
// with per-wave stats atomics (no final barrier).
__global__ __launch_bounds__(256) void convgn_kernel(
        const ushort_t* xbuf_1, const ushort_t* xbuf_2,
        const float* stats_in_1, const float* stats_in_2,
        const float* __restrict__ gam, const float* __restrict__ bet,
        const ushort_t* __restrict__ W2, const float* __restrict__ bias,
        ushort_t* ybuf_1, ushort_t* ybuf_2,
        float* stats_out_1, float* stats_out_2) {
    __shared__ ushort_t xt[64 * 136];
    __shared__ float sc[CC], sh[CC];
    int y = blockIdx.y;
    const ushort_t* xbuf = y ? xbuf_2 : xbuf_1;
    const float* stats_in = y ? stats_in_2 : stats_in_1;
    ushort_t* ybuf = y ? ybuf_2 : ybuf_1;
    float* stats_out = y ? stats_out_2 : stats_out_1;
    int tid = threadIdx.x;
    int s0 = blockIdx.x * 64;
    int b = s0 >> 16;
    if (tid < CC) {
        int g = tid >> 4;
        float S = 0.f, Q = 0.f;
        for (int s = 0; s < 32; ++s) {
            S += stats_in[s * 32 + (b * 8 + g) * 2];
            Q += stats_in[s * 32 + (b * 8 + g) * 2 + 1];
        }
        float mu = S / CNT_PER_GROUP;
        float var = Q / CNT_PER_GROUP - mu * mu;
        float rs = rsqrtf(var + 1e-5f);
        float scale = gam[tid] * rs;
        sc[tid] = scale;
        sh[tid] = bet[tid] - mu * scale;
    }
    __syncthreads();
    // cooperative staging: all 256 threads issue 4 independent u16x8 loads (MLP burst)
    #pragma unroll
    for (int j = 0; j < 4; ++j) {
        int idx = tid + 256 * j;
        int row = idx >> 4, c8 = (idx & 15) * 8;
        u16x8 vin = *(const u16x8*)&xbuf[(size_t)(s0 + row) * CC + c8];
        u16x8 vo;
        #pragma unroll
        for (int e = 0; e < 8; ++e) {
            float v = bf2f(vin[e]) * sc[c8 + e] + sh[c8 + e];
            v = v >= 0.f ? v : 0.1f * v;
            vo[e] = f2bf(v);
        }
        *(u16x8*)&xt[row * 136 + c8] = vo;
    }
    __syncthreads();
    int lane = tid & 63, wv = tid >> 6;
    int r0 = wv * 16;
    int quad = lane >> 4, r = lane & 15;
    f32x4 acc[8];
    #pragma unroll
    for (int t = 0; t < 8; ++t) acc[t] = (f32x4){0.f, 0.f, 0.f, 0.f};
    int aoff = (r0 + r) * 136 + quad * 8;
    #pragma unroll
    for (int kb = 0; kb < 4; ++kb) {
        bf16x8 a = *(const bf16x8*)&xt[aoff + kb * 32];
        const ushort_t* wb = W2 + (size_t)kb * 4096 + lane * 8;
        #pragma unroll
        for (int t = 0; t < 8; ++t) {
            bf16x8 bf = *(const bf16x8*)&wb[t * 512];
            acc[t] = __builtin_amdgcn_mfma_f32_16x16x32_bf16(a, bf, acc[t], 0, 0, 0);
        }
    }
    // epilogue: bias + per-wave stats atomics; stage bf16 into wave-private slab rows
    #pragma unroll
    for (int t = 0; t < 8; ++t) {
        int co = t * 16 + r;
        float bv = bias[co];
        float S = 0.f, Q = 0.f;
        #pragma unroll
        for (int reg = 0; reg < 4; ++reg) {
            int rl = r0 + quad * 4 + reg;
            float yv = acc[t][reg] + bv;
            xt[rl * 136 + co] = f2bf(yv);
            S += yv; Q += yv * yv;
        }
        #pragma unroll
        for (int off = 1; off < 64; off <<= 1) {
            S += __shfl_xor(S, off);
            Q += __shfl_xor(Q, off);
        }
        if (lane == 0) {
            int s = (blockIdx.x * 4 + wv) & 31;
            atomicAdd(&stats_out[s * 32 + (b * 8 + t) * 2],     S);
            atomicAdd(&stats_out[s * 32 + (b * 8 + t) * 2 + 1], Q);
        }
    }
    // wave-private slab -> coalesced 16B global stores (no barrier: own rows only)
    #pragma unroll
    for (int i = 0; i < 4; ++i) {
        int chunk = i * 64 + lane;             // row(4b) x c8(4b) within wave tile
        int rl = r0 + (chunk >> 4);
        int c8 = (chunk & 15) * 8;
        u16x8 v = *(const u16x8*)&xt[rl * 136 + c8];
        *(u16x8*)&ybuf[(size_t)(s0 + rl) * CC + c8] = v;
    }
}

// ------------------------------------------------- maxpool (cross3 tail), n-run writes
__global__ __launch_bounds__(256) void maxpool_kernel(
        const ushort_t* __restrict__ ybuf, const float* __restrict__ stats,
        const float* __restrict__ gam, const float* __restrict__ bet,
        float* __restrict__ outb) {
    int p0 = blockIdx.x * 16;
    int b = p0 >> 12, n0 = p0 & 4095;
    int tid = threadIdx.x;
    int c = tid & 127, half = tid >> 7;
    int g = c >> 4;
    float S = 0.f, Q = 0.f;
    for (int s = 0; s < 32; ++s) {
        S += stats[s * 32 + (b * 8 + g) * 2];
        Q += stats[s * 32 + (b * 8 + g) * 2 + 1];
    }
    float mu = S / CNT_PER_GROUP;
    float var = Q / CNT_PER_GROUP - mu * mu;
    float rs = rsqrtf(var + 1e-5f);
    float scale = gam[c] * rs;
    float shift = bet[c] - mu * scale;
    float* orow = outb + ((size_t)b * CC + c) * NPTS + n0 + half * 8;
    #pragma unroll
    for (int j = 0; j < 8; ++j) {
        int nl = half * 8 + j;
        float mx = -INFINITY;
        for (int k = 0; k < KNN; ++k) {
            float v = bf2f(ybuf[((size_t)(p0 + nl) * KNN + k) * CC + c]) * scale + shift;
            v = v >= 0.f ? v : 0.1f * v;
            mx = fmaxf(mx, v);
        }
        orow[j] = mx;
    }
}

// ------------------------------------------------- fused maxpool + conv (dual)
__global__ __launch_bounds__(256) void maxconv_kernel(
        const ushort_t* ybuf_1, const ushort_t* ybuf_2,
        const float* stats_1, const float* stats_2,
        const float* __restrict__ gam, const float* __restrict__ bet,
        const float* wT_1, const float* wT_2,
        const float* bias_1, const float* bias_2,
        float* outf_1, float* outf_2,
        float* __restrict__ outb) {
    __shared__ float mxs[16][CC + 4];
    int y = blockIdx.y;
    const ushort_t* ybuf = y ? ybuf_2 : ybuf_1;
    const float* stats = y ? stats_2 : stats_1;
    const float* wT = y ? wT_2 : wT_1;
    const float* bias = y ? bias_2 : bias_1;
    float* outf = y ? outf_2 : outf_1;
    float* ob = outb + (size_t)y * 2 * NPTS * CC;
    int p0 = blockIdx.x * 16;
    int b = p0 >> 12, n0 = p0 & 4095;
    int tid = threadIdx.x;
    int c = tid & 127, half = tid >> 7;
    int g = c >> 4;
    float S = 0.f, Q = 0.f;
    for (int s = 0; s < 32; ++s) {
        S += stats[s * 32 + (b * 8 + g) * 2];
        Q += stats[s * 32 + (b * 8 + g) * 2 + 1];
    }
    float mu = S / CNT_PER_GROUP;
    float var = Q / CNT_PER_GROUP - mu * mu;
    float rs = rsqrtf(var + 1e-5f);
    float scale = gam[c] * rs;
    float shift = bet[c] - mu * scale;
    #pragma unroll
    for (int j = 0; j < 8; ++j) {
        int nl = half * 8 + j;
        float mx = -INFINITY;
        for (int k = 0; k < KNN; ++k) {
            float v = bf2f(ybuf[((size_t)(p0 + nl) * KNN + k) * CC + c]) * scale + shift;
            v = v >= 0.f ? v : 0.1f * v;
            mx = fmaxf(mx, v);
        }
        mxs[nl][c] = mx;
    }
    __syncthreads();
    float acc[8];
    float bv = bias[c];
    #pragma unroll
    for (int j = 0; j < 8; ++j) acc[j] = bv;
    for (int ci = 0; ci < CC; ++ci) {
        float wv = wT[(size_t)ci * CC + c];
        #pragma unroll
        for (int j = 0; j < 8; ++j)
            acc[j] += wv * mxs[half * 8 + j][ci];
    }
    #pragma unroll
    for (int j = 0; j < 8; ++j)
        outf[(size_t)(p0 + half * 8 + j) * CC + c] = acc[j];
    float* orow = ob + ((size_t)b * CC + c) * NPTS + n0 + half * 8;
    #pragma unroll
    for (int j = 0; j < 8; ++j) orow[j] = acc[j];
}

extern "C" void kernel_launch(void* const* d_in, const int* in_sizes, int n_in,
                              void* d_out, int out_size, void* d_ws, size_t ws_size,
                              hipStream_t stream) {
    (void)in_sizes; (void)n_in; (void)out_size; (void)ws_size;
    const float* pc1    = (const float*)d_in[0];
    const float* pc2    = (const float*)d_in[1];
    const float* feat1  = (const float*)d_in[2];
    const float* feat2  = (const float*)d_in[3];
    const float* t11_w  = (const float*)d_in[4];
    const float* t11_b  = (const float*)d_in[5];
    const float* t22_w  = (const float*)d_in[6];
    const float* t22_b  = (const float*)d_in[7];
    const float* pos1_w = (const float*)d_in[8];
    const float* pos1_b = (const float*)d_in[9];
    const float* gn1_g  = (const float*)d_in[10];
    const float* gn1_b  = (const float*)d_in[11];
    const float* m1a_w  = (const float*)d_in[12];
    const float* m1a_b  = (const float*)d_in[13];
    const float* m1a_g  = (const float*)d_in[14];
    const float* m1a_be = (const float*)d_in[15];
    const float* m1b_w  = (const float*)d_in[16];
    const float* m1b_b  = (const float*)d_in[17];
    const float* m1b_g  = (const float*)d_in[18];
    const float* m1b_be = (const float*)d_in[19];
    const float* t1_w   = (const float*)d_in[20];
    const float* t1_b   = (const float*)d_in[21];
    const float* t2_w   = (const float*)d_in[22];
    const float* t2_b   = (const float*)d_in[23];
    const float* pos2_w = (const float*)d_in[24];
    const float* pos2_b = (const float*)d_in[25];
    const float* gn2_g  = (const float*)d_in[26];
    const float* gn2_b  = (const float*)d_in[27];
    const float* m2a_w  = (const float*)d_in[28];
    const float* m2a_b  = (const float*)d_in[29];
    const float* m2a_g  = (const float*)d_in[30];
    const float* m2a_be = (const float*)d_in[31];

    float* out = (float*)d_out;
    const size_t PN = 2 * NPTS;              // 8192 points
    const size_t PT = PN * CC;               // 1,048,576 elements per point-tensor
    float* ws   = (float*)d_ws;
    float* f1   = ws;
    float* f2   = f1 + PT;
    float* g1   = f2 + PT;
    float* g2   = g1 + PT;
    float* f1n  = g2 + PT;
    float* f2n  = f1n + PT;
    int*   idx12 = (int*)(f2n + PT);
    int*   idx21 = idx12 + PN * KNN;
    float* stats = (float*)(idx21 + PN * KNN);     // 8 stages * 1024
    float* wTt11 = stats + 8 * STAT_STRIDE;
    float* wTt22 = wTt11 + 64 * CC;
    float* wTt1  = wTt22 + 64 * CC;
    float* wTt2  = wTt1 + CC * CC;
    ushort_t* W2m1a = (ushort_t*)(wTt2 + CC * CC);
    ushort_t* W2m1b = W2m1a + 16384;
    ushort_t* W2m2a = W2m1b + 16384;
    ushort_t* bufX1 = W2m2a + 16384;               // bf16 [PN*KNN*CC] each
    ushort_t* bufY1 = bufX1 + (size_t)PN * KNN * CC;
    ushort_t* bufX2 = bufY1 + (size_t)PN * KNN * CC;
    ushort_t* bufY2 = bufX2 + (size_t)PN * KNN * CC;

    prep_kernel<<<dim3(64, 8), 256, 0, stream>>>(
        t11_w, t22_w, t1_w, t2_w, m1a_w, m1b_w, m2a_w,
        wTt11, wTt22, wTt1, wTt2, W2m1a, W2m1b, W2m2a, stats);

    conv64_kernel<<<dim3(PN / 64, 4), 256, 0, stream>>>(
        feat1, feat2, wTt11, wTt22, t11_b, t22_b, f1, f2, g1, g2);
    knn_kernel<<<dim3(PN / 32, 2), 512, 0, stream>>>(pc1, pc2, idx12, idx21);

    float* st0 = stats;
    // ---- cross1 + cross2 merged (independent pipelines, blockIdx.y selects)
    h0_kernel<<<dim3(PN, 2), 128, 0, stream>>>(
        f1, f2, g1, g2, pc1, pc2, idx12, idx21, pos1_w, pos1_b,
        bufX1, bufX2, st0 + 0 * STAT_STRIDE, st0 + 3 * STAT_STRIDE);
    convgn_kernel<<<dim3(2048, 2), 256, 0, stream>>>(
        bufX1, bufX2, st0 + 0 * STAT_STRIDE, st0 + 3 * STAT_STRIDE,
        gn1_g, gn1_b, W2m1a, m1a_b,
        bufY1, bufY2, st0 + 1 * STAT_STRIDE, st0 + 4 * STAT_STRIDE);
    convgn_kernel<<<dim3(2048, 2), 256, 0, stream>>>(
        bufY1, bufY2, st0 + 1 * STAT_STRIDE, st0 + 4 * STAT_STRIDE,
        m1a_g, m1a_be, W2m1b, m1b_b,
        bufX1, bufX2, st0 + 2 * STAT_STRIDE, st0 + 5 * STAT_STRIDE);
    maxconv_kernel<<<dim3(PN / 16, 2), 256, 0, stream>>>(
        bufX1, bufX2, st0 + 2 * STAT_STRIDE, st0 + 5 * STAT_STRIDE,
        m1b_g, m1b_be, wTt1, wTt2, t1_b, t2_b, f1n, f2n, out);

    // ---- cross3: (pc1, pc2, feat1_new, feat2_new) -> feat1_final
    h0_kernel<<<dim3(PN, 1), 128, 0, stream>>>(
        f1n, f2n, f1n, f2n, pc1, pc2, idx12, idx12, pos2_w, pos2_b,
        bufX1, bufX1, st0 + 6 * STAT_STRIDE, st0 + 6 * STAT_STRIDE);
    convgn_kernel<<<dim3(2048, 1), 256, 0, stream>>>(
        bufX1, bufX1, st0 + 6 * STAT_STRIDE, st0 + 6 * STAT_STRIDE,
        gn2_g, gn2_b, W2m2a, m2a_b,
        bufY1, bufY1, st0 + 7 * STAT_STRIDE, st0 + 7 * STAT_STRIDE);
    maxpool_kernel<<<PN / 16, 256, 0, stream>>>(
        bufY1, st0 + 7 * STAT_STRIDE, m2a_g, m2a_be, out + 2 * PT);
}

// Round 15
// 375.725 us; speedup vs baseline: 1.5206x; 1.4722x over previous
//
#include <hip/hip_runtime.h>
#include <hip/hip_bf16.h>

#define NPTS 4096
#define CC   128
#define KNN  16
#define CNT_PER_GROUP 1048576.0f  // 16 ch * 4096 n * 16 k
#define STAT_STRIDE 1024          // 32 partial slots x [b(2) x g(8) x 2]

typedef __attribute__((ext_vector_type(8))) short bf16x8;
typedef __attribute__((ext_vector_type(8))) unsigned short u16x8;
typedef __attribute__((ext_vector_type(4))) float f32x4;
typedef unsigned short ushort_t;

static __device__ __forceinline__ ushort_t f2bf(float f) {
    __hip_bfloat16 h = __float2bfloat16(f);   // RNE
    ushort_t u; __builtin_memcpy(&u, &h, 2);
    return u;
}
static __device__ __forceinline__ float bf2f(ushort_t u) {
    unsigned v = (unsigned)u << 16;
    float f; __builtin_memcpy(&f, &v, 4);
    return f;
}

// ---------------------------------------------------------------- prep
__global__ void prep_kernel(const float* __restrict__ t11_w, const float* __restrict__ t22_w,
                            const float* __restrict__ t1_w,  const float* __restrict__ t2_w,
                            const float* __restrict__ m1a_w, const float* __restrict__ m1b_w,
                            const float* __restrict__ m2a_w,
                            float* __restrict__ wTt11, float* __restrict__ wTt22,
                            float* __restrict__ wTt1,  float* __restrict__ wTt2,
                            ushort_t* __restrict__ W2m1a, ushort_t* __restrict__ W2m1b,
                            ushort_t* __restrict__ W2m2a, float* __restrict__ stats) {
    int y = blockIdx.y;
    int idx = blockIdx.x * 256 + threadIdx.x;
    if (y == 7) {
        if (idx < 8 * STAT_STRIDE) stats[idx] = 0.0f;
        return;
    }
    if (y < 4) {
        const float* in; float* outp; int Cdim;
        switch (y) {
            case 0: in = t11_w; outp = wTt11; Cdim = 64; break;
            case 1: in = t22_w; outp = wTt22; Cdim = 64; break;
            case 2: in = t1_w;  outp = wTt1;  Cdim = CC; break;
            default: in = t2_w; outp = wTt2;  Cdim = CC; break;
        }
        if (idx < CC * Cdim) {
            int o = idx / Cdim, c = idx % Cdim;
            outp[c * CC + o] = in[idx];
        }
        return;
    }
    const float* in = y == 4 ? m1a_w : y == 5 ? m1b_w : m2a_w;
    ushort_t* outp  = y == 4 ? W2m1a : y == 5 ? W2m1b : W2m2a;
    if (idx < 16384) {
        int j = idx & 7, lane = (idx >> 3) & 63, coT = (idx >> 9) & 7, kb = idx >> 12;
        int k  = kb * 32 + (lane >> 4) * 8 + j;
        int co = coT * 16 + (lane & 15);
        outp[idx] = f2bf(in[co * CC + k]);
    }
}

// ------------------------------------------------- conv1d 64->128, LDS-staged tile GEMM
__global__ __launch_bounds__(256) void conv64_kernel(
        const float* __restrict__ feat1, const float* __restrict__ feat2,
        const float* __restrict__ wTt11, const float* __restrict__ wTt22,
        const float* __restrict__ b11, const float* __restrict__ b22,
        float* __restrict__ f1, float* __restrict__ f2,
        float* __restrict__ g1, float* __restrict__ g2) {
    __shared__ float xs[64][68];
    int y = blockIdx.y;
    const float* x  = (y == 0 || y == 3) ? feat1 : feat2;
    const float* wT = (y == 0 || y == 2) ? wTt11 : wTt22;
    const float* bias = (y == 0 || y == 2) ? b11 : b22;
    float* outp = y == 0 ? f1 : y == 1 ? f2 : y == 2 ? g1 : g2;
    int tid = threadIdx.x;
    int n0 = blockIdx.x * 64;
    int b = n0 >> 12, nloc = n0 & 4095;
    const float* xb = x + (size_t)b * 64 * NPTS + nloc;
    #pragma unroll
    for (int i = 0; i < 16; ++i) {
        int e = tid + 256 * i;
        int ci = e >> 6, nn = e & 63;
        xs[ci][nn] = xb[(size_t)ci * NPTS + nn];
    }
    __syncthreads();
    int co = (tid & 31) * 4;
    int r0 = (tid >> 5) * 8;
    float acc[4][8];
    float4 bv = *(const float4*)&bias[co];
    #pragma unroll
    for (int j = 0; j < 8; ++j) { acc[0][j] = bv.x; acc[1][j] = bv.y; acc[2][j] = bv.z; acc[3][j] = bv.w; }
    for (int ci = 0; ci < 64; ++ci) {
        float4 wv = *(const float4*)&wT[(size_t)ci * CC + co];
        #pragma unroll
        for (int j = 0; j < 8; ++j) {
            float xv = xs[ci][r0 + j];
            acc[0][j] += wv.x * xv;
            acc[1][j] += wv.y * xv;
            acc[2][j] += wv.z * xv;
            acc[3][j] += wv.w * xv;
        }
    }
    #pragma unroll
    for (int j = 0; j < 8; ++j) {
        *(float4*)&outp[(size_t)(n0 + r0 + j) * CC + co] =
            make_float4(acc[0][j], acc[1][j], acc[2][j], acc[3][j]);
    }
}

// ---------------------------------------------------------------- 64-bit shuffles
static __device__ __forceinline__ unsigned long long sxor64(unsigned long long v, int m) {
    unsigned lo = (unsigned)__shfl_xor((int)(unsigned)v, m);
    unsigned hi = (unsigned)__shfl_xor((int)(v >> 32), m);
    return ((unsigned long long)hi << 32) | lo;
}

// ------------------------------------------------- KNN: atomic-append pass 2
__global__ __launch_bounds__(512) void knn_kernel(
        const float* __restrict__ pc1, const float* __restrict__ pc2,
        int* __restrict__ idx12, int* __restrict__ idx21) {
#pragma clang fp contract(off)
    __shared__ float4 pk[NPTS];                           // 64 KB
    __shared__ unsigned long long lst[8][4][63];          // 15.75 KB
    __shared__ int cnt[8][4];                             // 128 B
    int dir = blockIdx.y;
    const float* qs = dir ? pc2 : pc1;
    const float* cs = dir ? pc1 : pc2;
    int* outIdx = dir ? idx21 : idx12;
    int tid = threadIdx.x, lane = tid & 63, wv = tid >> 6;
    int qbase = blockIdx.x * 32;
    int b = qbase >> 12;
    const float* cb = cs + (size_t)b * 3 * NPTS;
    for (int i = tid; i < NPTS; i += 512) {
        float x = cb[i], y = cb[NPTS + i], z = cb[2 * NPTS + i];
        pk[i] = make_float4(x, y, z, x * x + y * y + z * z);  // l2r, no fma
    }
    __syncthreads();
    const float* qb = qs + (size_t)b * 3 * NPTS;
    int q0 = qbase + wv * 4;
    float qx[4], qy[4], qz[4], s1[4], dmin[4], T[4];
    #pragma unroll
    for (int t = 0; t < 4; ++t) {
        int n = (q0 + t) & 4095;
        qx[t] = qb[n]; qy[t] = qb[NPTS + n]; qz[t] = qb[2 * NPTS + n];
        s1[t] = qx[t] * qx[t] + qy[t] * qy[t] + qz[t] * qz[t];
        dmin[t] = 1e30f;
    }
    for (int j = 0; j < 64; ++j) {
        float4 P = pk[j * 64 + lane];
        #pragma unroll
        for (int t = 0; t < 4; ++t) {
            float dt = __builtin_fmaf(P.z, qz[t], __builtin_fmaf(P.y, qy[t], P.x * qx[t]));
            float d2 = (s1[t] + P.w) - 2.0f * dt;
            dmin[t] = fminf(dmin[t], d2);
        }
    }
    #pragma unroll
    for (int t = 0; t < 4; ++t) {
        float sv = dmin[t];
        for (int k = 2; k <= 64; k <<= 1)
            for (int j = k >> 1; j > 0; j >>= 1) {
                float o = __shfl_xor(sv, j);
                bool tmin = (((lane & k) == 0) == ((lane & j) == 0));
                sv = tmin ? fminf(sv, o) : fmaxf(sv, o);
            }
        T[t] = __shfl(sv, 15);
    }
    if (lane < 4) cnt[wv][lane] = 0;
    for (int j = 0; j < 64; ++j) {
        float4 P = pk[j * 64 + lane];
        int m = j * 64 + lane;
        #pragma unroll
        for (int t = 0; t < 4; ++t) {
            float dt = __builtin_fmaf(P.z, qz[t], __builtin_fmaf(P.y, qy[t], P.x * qx[t]));
            float d2 = (s1[t] + P.w) - 2.0f * dt;
            if (d2 <= T[t]) {
                unsigned u = __float_as_uint(d2);
                u ^= (unsigned)(((int)u >> 31) | 0x80000000);
                int pos = atomicAdd(&cnt[wv][t], 1);
                if (pos < 63) lst[wv][t][pos] = ((unsigned long long)u << 32) | (unsigned)m;
            }
        }
    }
    #pragma unroll
    for (int t = 0; t < 4; ++t) {
        int nT = cnt[wv][t]; if (nT > 63) nT = 63;
        unsigned long long key = (lane < nT) ? lst[wv][t][lane] : ~0ULL;
        for (int k = 2; k <= 64; k <<= 1)
            for (int j = k >> 1; j > 0; j >>= 1) {
                unsigned long long o = sxor64(key, j);
                bool tmin = (((lane & k) == 0) == ((lane & j) == 0));
                unsigned long long mn = key < o ? key : o;
                unsigned long long mx = key < o ? o : key;
                key = tmin ? mn : mx;
            }
        if (lane < KNN) outIdx[(size_t)(q0 + t) * KNN + lane] = (int)(unsigned)(key & 0xFFFFFFFFULL);
    }
}

// ------------------------------------------------- h0 (dual: cross1 / cross2 by blockIdx.y)
__global__ void h0_kernel(const float* p1f_1, const float* p2f_1,
                          const float* p1f_2, const float* p2f_2,
                          const float* __restrict__ pc1, const float* __restrict__ pc2,
                          const int* idx_1, const int* idx_2,
                          const float* __restrict__ pos_w, const float* __restrict__ pos_b,
                          ushort_t* buf_1, ushort_t* buf_2,
                          float* stats_1, float* stats_2) {
    __shared__ float redS[128], redQ[128];
    int y = blockIdx.y;
    const float* p1f = y ? p1f_2 : p1f_1;
    const float* p2f = y ? p2f_2 : p2f_1;
    const float* pcA = y ? pc2 : pc1;
    const float* pcB = y ? pc1 : pc2;
    const int* idx = y ? idx_2 : idx_1;
    ushort_t* buf = y ? buf_2 : buf_1;
    float* stats_out = y ? stats_2 : stats_1;
    int p = blockIdx.x;                    // b*N + n
    int b = p >> 12, n = p & 4095;
    int c = threadIdx.x;
    float pw0 = pos_w[c * 3], pw1 = pos_w[c * 3 + 1], pw2 = pos_w[c * 3 + 2];
    float pb = pos_b[c];
    float p1v = p1f[(size_t)p * CC + c];
    const float* pa = pcA + (size_t)b * 3 * NPTS;
    const float* pc = pcB + (size_t)b * 3 * NPTS;
    float qx = pa[n], qy = pa[NPTS + n], qz = pa[2 * NPTS + n];
    float S = 0.f, Q = 0.f;
    for (int k = 0; k < KNN; ++k) {
        int m = idx[(size_t)p * KNN + k];
        float dx = pc[m] - qx;
        float dy = pc[NPTS + m] - qy;
        float dz = pc[2 * NPTS + m] - qz;
        float pos = pw0 * dx + pw1 * dy + pw2 * dz + pb;
        float v = p2f[((size_t)b * NPTS + m) * CC + c] + p1v + pos;
        buf[((size_t)p * KNN + k) * CC + c] = f2bf(v);
        S += v; Q += v * v;
    }
    redS[c] = S; redQ[c] = Q;
    __syncthreads();
    if (c < 8) {
        float SS = 0.f, QQ = 0.f;
        for (int i = 0; i < 16; ++i) { SS += redS[c * 16 + i]; QQ += redQ[c * 16 + i]; }
        int s = blockIdx.x & 31;
        atomicAdd(&stats_out[s * 32 + (b * 8 + c) * 2],     SS);
        atomicAdd(&stats_out[s * 32 + (b * 8 + c) * 2 + 1], QQ);
    }
}

// ------------------------------------------------- convgn v5 (dual): 128-row tiles,
// R12 stats structure (LDS merge + final barrier + 16 atomics/block by tid<8).
__global__ __launch_bounds__(256) void convgn_kernel(
        const ushort_t* xbuf_1, const ushort_t* xbuf_2,
        const float* stats_in_1, const float* stats_in_2,
        const float* __restrict__ gam, const float* __restrict__ bet,
        const ushort_t* __restrict__ W2, const float* __restrict__ bias,
        ushort_t* ybuf_1, ushort_t* ybuf_2,
        float* stats_out_1, float* stats_out_2) {
    __shared__ ushort_t xt[128 * 136];     // 34816 B
    __shared__ float sc[CC], sh[CC];
    __shared__ float redS[4][8], redQ[4][8];
    int y = blockIdx.y;
    const ushort_t* xbuf = y ? xbuf_2 : xbuf_1;
    const float* stats_in = y ? stats_in_2 : stats_in_1;
    ushort_t* ybuf = y ? ybuf_2 : ybuf_1;
    float* stats_out = y ? stats_out_2 : stats_out_1;
    int tid = threadIdx.x;
    int s0 = blockIdx.x * 128;             // 128 rows, never crosses b (65536 % 128 == 0)
    int b = s0 >> 16;
    if (tid < CC) {
        int g = tid >> 4;
        float S = 0.f, Q = 0.f;
        for (int s = 0; s < 32; ++s) {
            S += stats_in[s * 32 + (b * 8 + g) * 2];
            Q += stats_in[s * 32 + (b * 8 + g) * 2 + 1];
        }
        float mu = S / CNT_PER_GROUP;
        float var = Q / CNT_PER_GROUP - mu * mu;
        float rs = rsqrtf(var + 1e-5f);
        float scale = gam[tid] * rs;
        sc[tid] = scale;
        sh[tid] = bet[tid] - mu * scale;
    }
    __syncthreads();
    // cooperative staging: 256 threads x 8 independent u16x8 loads = 32 KB burst
    #pragma unroll
    for (int j = 0; j < 8; ++j) {
        int idx = tid + 256 * j;           // 2048 chunks = 128 rows x 16
        int row = idx >> 4, c8 = (idx & 15) * 8;
        u16x8 vin = *(const u16x8*)&xbuf[(size_t)(s0 + row) * CC + c8];
        u16x8 vo;
        #pragma unroll
        for (int e = 0; e < 8; ++e) {
            float v = bf2f(vin[e]) * sc[c8 + e] + sh[c8 + e];
            v = v >= 0.f ? v : 0.1f * v;
            vo[e] = f2bf(v);
        }
        *(u16x8*)&xt[row * 136 + c8] = vo;
    }
    __syncthreads();
    int lane = tid & 63, wv = tid >> 6;
    int r0 = wv * 32;                      // wave owns 32 rows = 2 MFMA row-groups
    int quad = lane >> 4, r = lane & 15;
    f32x4 acc[2][8];
    #pragma unroll
    for (int h = 0; h < 2; ++h)
        #pragma unroll
        for (int t = 0; t < 8; ++t) acc[h][t] = (f32x4){0.f, 0.f, 0.f, 0.f};
    int aoff0 = (r0 + r) * 136 + quad * 8;
    int aoff1 = (r0 + 16 + r) * 136 + quad * 8;
    #pragma unroll
    for (int kb = 0; kb < 4; ++kb) {
        bf16x8 a0 = *(const bf16x8*)&xt[aoff0 + kb * 32];
        bf16x8 a1 = *(const bf16x8*)&xt[aoff1 + kb * 32];
        const ushort_t* wb = W2 + (size_t)kb * 4096 + lane * 8;
        #pragma unroll
        for (int t = 0; t < 8; ++t) {
            bf16x8 bf = *(const bf16x8*)&wb[t * 512];   // shared across both row-groups
            acc[0][t] = __builtin_amdgcn_mfma_f32_16x16x32_bf16(a0, bf, acc[0][t], 0, 0, 0);
            acc[1][t] = __builtin_amdgcn_mfma_f32_16x16x32_bf16(a1, bf, acc[1][t], 0, 0, 0);
        }
    }
    // epilogue: bias, stage bf16 into wave-private slab rows, per-wave shuffle stats
    #pragma unroll
    for (int t = 0; t < 8; ++t) {
        int co = t * 16 + r;
        float bv = bias[co];
        float S = 0.f, Q = 0.f;
        #pragma unroll
        for (int h = 0; h < 2; ++h) {
            #pragma unroll
            for (int reg = 0; reg < 4; ++reg) {
                int rl = r0 + h * 16 + quad * 4 + reg;
                float yv = acc[h][t][reg] + bv;
                xt[rl * 136 + co] = f2bf(yv);
                S += yv; Q += yv * yv;
            }
        }
        #pragma unroll
        for (int off = 1; off < 64; off <<= 1) {
            S += __shfl_xor(S, off);
            Q += __shfl_xor(Q, off);
        }
        if (lane == 0) { redS[wv][t] = S; redQ[wv][t] = Q; }
    }
    // wave-private slab -> coalesced 16B global stores (no barrier: own rows only)
    #pragma unroll
    for (int i = 0; i < 8; ++i) {
        int chunk = i * 64 + lane;             // 512 chunks = 32 rows x 16
        int rl = r0 + (chunk >> 4);
        int c8 = (chunk & 15) * 8;
        u16x8 v = *(const u16x8*)&xt[rl * 136 + c8];
        *(u16x8*)&ybuf[(size_t)(s0 + rl) * CC + c8] = v;
    }
    __syncthreads();
    if (tid < 8) {
        float S = redS[0][tid] + redS[1][tid] + redS[2][tid] + redS[3][tid];
        float Q = redQ[0][tid] + redQ[1][tid] + redQ[2][tid] + redQ[3][tid];
        int s = blockIdx.x & 31;
        atomicAdd(&stats_out[s * 32 + (b * 8 + tid) * 2],     S);
        atomicAdd(&stats_out[s * 32 + (b * 8 + tid) * 2 + 1], Q);
    }
}

// ------------------------------------------------- maxpool (cross3 tail), n-run writes
__global__ __launch_bounds__(256) void maxpool_kernel(
        const ushort_t* __restrict__ ybuf, const float* __restrict__ stats,
        const float* __restrict__ gam, const float* __restrict__ bet,
        float* __restrict__ outb) {
    int p0 = blockIdx.x * 16;
    int b = p0 >> 12, n0 = p0 & 4095;
    int tid = threadIdx.x;
    int c = tid & 127, half = tid >> 7;
    int g = c >> 4;
    float S = 0.f, Q = 0.f;
    for (int s = 0; s < 32; ++s) {
        S += stats[s * 32 + (b * 8 + g) * 2];
        Q += stats[s * 32 + (b * 8 + g) * 2 + 1];
    }
    float mu = S / CNT_PER_GROUP;
    float var = Q / CNT_PER_GROUP - mu * mu;
    float rs = rsqrtf(var + 1e-5f);
    float scale = gam[c] * rs;
    float shift = bet[c] - mu * scale;
    float* orow = outb + ((size_t)b * CC + c) * NPTS + n0 + half * 8;
    #pragma unroll
    for (int j = 0; j < 8; ++j) {
        int nl = half * 8 + j;
        float mx = -INFINITY;
        for (int k = 0; k < KNN; ++k) {
            float v = bf2f(ybuf[((size_t)(p0 + nl) * KNN + k) * CC + c]) * scale + shift;
            v = v >= 0.f ? v : 0.1f * v;
            mx = fmaxf(mx, v);
        }
        orow[j] = mx;
    }
}

// ------------------------------------------------- fused maxpool + conv (dual)
__global__ __launch_bounds__(256) void maxconv_kernel(
        const ushort_t* ybuf_1, const ushort_t* ybuf_2,
        const float* stats_1, const float* stats_2,
        const float* __restrict__ gam, const float* __restrict__ bet,
        const float* wT_1, const float* wT_2,
        const float* bias_1, const float* bias_2,
        float* outf_1, float* outf_2,
        float* __restrict__ outb) {
    __shared__ float mxs[16][CC + 4];
    int y = blockIdx.y;
    const ushort_t* ybuf = y ? ybuf_2 : ybuf_1;
    const float* stats = y ? stats_2 : stats_1;
    const float* wT = y ? wT_2 : wT_1;
    const float* bias = y ? bias_2 : bias_1;
    float* outf = y ? outf_2 : outf_1;
    float* ob = outb + (size_t)y * 2 * NPTS * CC;
    int p0 = blockIdx.x * 16;
    int b = p0 >> 12, n0 = p0 & 4095;
    int tid = threadIdx.x;
    int c = tid & 127, half = tid >> 7;
    int g = c >> 4;
    float S = 0.f, Q = 0.f;
    for (int s = 0; s < 32; ++s) {
        S += stats[s * 32 + (b * 8 + g) * 2];
        Q += stats[s * 32 + (b * 8 + g) * 2 + 1];
    }
    float mu = S / CNT_PER_GROUP;
    float var = Q / CNT_PER_GROUP - mu * mu;
    float rs = rsqrtf(var + 1e-5f);
    float scale = gam[c] * rs;
    float shift = bet[c] - mu * scale;
    #pragma unroll
    for (int j = 0; j < 8; ++j) {
        int nl = half * 8 + j;
        float mx = -INFINITY;
        for (int k = 0; k < KNN; ++k) {
            float v = bf2f(ybuf[((size_t)(p0 + nl) * KNN + k) * CC + c]) * scale + shift;
            v = v >= 0.f ? v : 0.1f * v;
            mx = fmaxf(mx, v);
        }
        mxs[nl][c] = mx;
    }
    __syncthreads();
    float acc[8];
    float bv = bias[c];
    #pragma unroll
    for (int j = 0; j < 8; ++j) acc[j] = bv;
    for (int ci = 0; ci < CC; ++ci) {
        float wv = wT[(size_t)ci * CC + c];
        #pragma unroll
        for (int j = 0; j < 8; ++j)
            acc[j] += wv * mxs[half * 8 + j][ci];
    }
    #pragma unroll
    for (int j = 0; j < 8; ++j)
        outf[(size_t)(p0 + half * 8 + j) * CC + c] = acc[j];
    float* orow = ob + ((size_t)b * CC + c) * NPTS + n0 + half * 8;
    #pragma unroll
    for (int j = 0; j < 8; ++j) orow[j] = acc[j];
}

extern "C" void kernel_launch(void* const* d_in, const int* in_sizes, int n_in,
                              void* d_out, int out_size, void* d_ws, size_t ws_size,
                              hipStream_t stream) {
    (void)in_sizes; (void)n_in; (void)out_size; (void)ws_size;
    const float* pc1    = (const float*)d_in[0];
    const float* pc2    = (const float*)d_in[1];
    const float* feat1  = (const float*)d_in[2];
    const float* feat2  = (const float*)d_in[3];
    const float* t11_w  = (const float*)d_in[4];
    const float* t11_b  = (const float*)d_in[5];
    const float* t22_w  = (const float*)d_in[6];
    const float* t22_b  = (const float*)d_in[7];
    const float* pos1_w = (const float*)d_in[8];
    const float* pos1_b = (const float*)d_in[9];
    const float* gn1_g  = (const float*)d_in[10];
    const float* gn1_b  = (const float*)d_in[11];
    const float* m1a_w  = (const float*)d_in[12];
    const float* m1a_b  = (const float*)d_in[13];
    const float* m1a_g  = (const float*)d_in[14];
    const float* m1a_be = (const float*)d_in[15];
    const float* m1b_w  = (const float*)d_in[16];
    const float* m1b_b  = (const float*)d_in[17];
    const float* m1b_g  = (const float*)d_in[18];
    const float* m1b_be = (const float*)d_in[19];
    const float* t1_w   = (const float*)d_in[20];
    const float* t1_b   = (const float*)d_in[21];
    const float* t2_w   = (const float*)d_in[22];
    const float* t2_b   = (const float*)d_in[23];
    const float* pos2_w = (const float*)d_in[24];
    const float* pos2_b = (const float*)d_in[25];
    const float* gn2_g  = (const float*)d_in[26];
    const float* gn2_b  = (const float*)d_in[27];
    const float* m2a_w  = (const float*)d_in[28];
    const float* m2a_b  = (const float*)d_in[29];
    const float* m2a_g  = (const float*)d_in[30];
    const float* m2a_be = (const float*)d_in[31];

    float* out = (float*)d_out;
    const size_t PN = 2 * NPTS;              // 8192 points
    const size_t PT = PN * CC;               // 1,048,576 elements per point-tensor
    float* ws   = (float*)d_ws;
    float* f1   = ws;
    float* f2   = f1 + PT;
    float* g1   = f2 + PT;
    float* g2   = g1 + PT;
    float* f1n  = g2 + PT;
    float* f2n  = f1n + PT;
    int*   idx12 = (int*)(f2n + PT);
    int*   idx21 = idx12 + PN * KNN;
    float* stats = (float*)(idx21 + PN * KNN);     // 8 stages * 1024
    float* wTt11 = stats + 8 * STAT_STRIDE;
    float* wTt22 = wTt11 + 64 * CC;
    float* wTt1  = wTt22 + 64 * CC;
    float* wTt2  = wTt1 + CC * CC;
    ushort_t* W2m1a = (ushort_t*)(wTt2 + CC * CC);
    ushort_t* W2m1b = W2m1a + 16384;
    ushort_t* W2m2a = W2m1b + 16384;
    ushort_t* bufX1 = W2m2a + 16384;               // bf16 [PN*KNN*CC] each
    ushort_t* bufY1 = bufX1 + (size_t)PN * KNN * CC;
    ushort_t* bufX2 = bufY1 + (size_t)PN * KNN * CC;
    ushort_t* bufY2 = bufX2 + (size_t)PN * KNN * CC;

    prep_kernel<<<dim3(64, 8), 256, 0, stream>>>(
        t11_w, t22_w, t1_w, t2_w, m1a_w, m1b_w, m2a_w,
        wTt11, wTt22, wTt1, wTt2, W2m1a, W2m1b, W2m2a, stats);

    conv64_kernel<<<dim3(PN / 64, 4), 256, 0, stream>>>(
        feat1, feat2, wTt11, wTt22, t11_b, t22_b, f1, f2, g1, g2);
    knn_kernel<<<dim3(PN / 32, 2), 512, 0, stream>>>(pc1, pc2, idx12, idx21);

    float* st0 = stats;
    // ---- cross1 + cross2 merged (independent pipelines, blockIdx.y selects)
    h0_kernel<<<dim3(PN, 2), 128, 0, stream>>>(
        f1, f2, g1, g2, pc1, pc2, idx12, idx21, pos1_w, pos1_b,
        bufX1, bufX2, st0 + 0 * STAT_STRIDE, st0 + 3 * STAT_STRIDE);
    convgn_kernel<<<dim3(1024, 2), 256, 0, stream>>>(
        bufX1, bufX2, st0 + 0 * STAT_STRIDE, st0 + 3 * STAT_STRIDE,
        gn1_g, gn1_b, W2m1a, m1a_b,
        bufY1, bufY2, st0 + 1 * STAT_STRIDE, st0 + 4 * STAT_STRIDE);
    convgn_kernel<<<dim3(1024, 2), 256, 0, stream>>>(
        bufY1, bufY2, st0 + 1 * STAT_STRIDE, st0 + 4 * STAT_STRIDE,
        m1a_g, m1a_be, W2m1b, m1b_b,
        bufX1, bufX2, st0 + 2 * STAT_STRIDE, st0 + 5 * STAT_STRIDE);
    maxconv_kernel<<<dim3(PN / 16, 2), 256, 0, stream>>>(
        bufX1, bufX2, st0 + 2 * STAT_STRIDE, st0 + 5 * STAT_STRIDE,
        m1b_g, m1b_be, wTt1, wTt2, t1_b, t2_b, f1n, f2n, out);

    // ---- cross3: (pc1, pc2, feat1_new, feat2_new) -> feat1_final
    h0_kernel<<<dim3(PN, 1), 128, 0, stream>>>(
        f1n, f2n, f1n, f2n, pc1, pc2, idx12, idx12, pos2_w, pos2_b,
        bufX1, bufX1, st0 + 6 * STAT_STRIDE, st0 + 6 * STAT_STRIDE);
    convgn_kernel<<<dim3(1024, 1), 256, 0, stream>>>(
        bufX1, bufX1, st0 + 6 * STAT_STRIDE, st0 + 6 * STAT_STRIDE,
        gn2_g, gn2_b, W2m2a, m2a_b,
        bufY1, bufY1, st0 + 7 * STAT_STRIDE, st0 + 7 * STAT_STRIDE);
    maxpool_kernel<<<PN / 16, 256, 0, stream>>>(
        bufY1, st0 + 7 * STAT_STRIDE, m2a_g, m2a_be, out + 2 * PT);
}

// Round 16
// 372.293 us; speedup vs baseline: 1.5346x; 1.0092x over previous
//
#include <hip/hip_runtime.h>
#include <hip/hip_bf16.h>

#define NPTS 4096
#define CC   128
#define KNN  16
#define CNT_PER_GROUP 1048576.0f  // 16 ch * 4096 n * 16 k
#define STAT_STRIDE 1024          // 32 partial slots x [b(2) x g(8) x 2]

typedef __attribute__((ext_vector_type(8))) short bf16x8;
typedef __attribute__((ext_vector_type(8))) unsigned short u16x8;
typedef __attribute__((ext_vector_type(4))) float f32x4;
typedef unsigned short ushort_t;

static __device__ __forceinline__ ushort_t f2bf(float f) {
    __hip_bfloat16 h = __float2bfloat16(f);   // RNE
    ushort_t u; __builtin_memcpy(&u, &h, 2);
    return u;
}
static __device__ __forceinline__ float bf2f(ushort_t u) {
    unsigned v = (unsigned)u << 16;
    float f; __builtin_memcpy(&f, &v, 4);
    return f;
}

// ---------------------------------------------------------------- prep
__global__ void prep_kernel(const float* __restrict__ t11_w, const float* __restrict__ t22_w,
                            const float* __restrict__ t1_w,  const float* __restrict__ t2_w,
                            const float* __restrict__ m1a_w, const float* __restrict__ m1b_w,
                            const float* __restrict__ m2a_w,
                            float* __restrict__ wTt11, float* __restrict__ wTt22,
                            float* __restrict__ wTt1,  float* __restrict__ wTt2,
                            ushort_t* __restrict__ W2m1a, ushort_t* __restrict__ W2m1b,
                            ushort_t* __restrict__ W2m2a, float* __restrict__ stats) {
    int y = blockIdx.y;
    int idx = blockIdx.x * 256 + threadIdx.x;
    if (y == 7) {
        if (idx < 8 * STAT_STRIDE) stats[idx] = 0.0f;
        return;
    }
    if (y < 4) {
        const float* in; float* outp; int Cdim;
        switch (y) {
            case 0: in = t11_w; outp = wTt11; Cdim = 64; break;
            case 1: in = t22_w; outp = wTt22; Cdim = 64; break;
            case 2: in = t1_w;  outp = wTt1;  Cdim = CC; break;
            default: in = t2_w; outp = wTt2;  Cdim = CC; break;
        }
        if (idx < CC * Cdim) {
            int o = idx / Cdim, c = idx % Cdim;
            outp[c * CC + o] = in[idx];
        }
        return;
    }
    const float* in = y == 4 ? m1a_w : y == 5 ? m1b_w : m2a_w;
    ushort_t* outp  = y == 4 ? W2m1a : y == 5 ? W2m1b : W2m2a;
    if (idx < 16384) {
        int j = idx & 7, lane = (idx >> 3) & 63, coT = (idx >> 9) & 7, kb = idx >> 12;
        int k  = kb * 32 + (lane >> 4) * 8 + j;
        int co = coT * 16 + (lane & 15);
        outp[idx] = f2bf(in[co * CC + k]);
    }
}

// ------------------------------------------------- conv1d 64->128, LDS-staged tile GEMM
__global__ __launch_bounds__(256) void conv64_kernel(
        const float* __restrict__ feat1, const float* __restrict__ feat2,
        const float* __restrict__ wTt11, const float* __restrict__ wTt22,
        const float* __restrict__ b11, const float* __restrict__ b22,
        float* __restrict__ f1, float* __restrict__ f2,
        float* __restrict__ g1, float* __restrict__ g2) {
    __shared__ float xs[64][68];
    int y = blockIdx.y;
    const float* x  = (y == 0 || y == 3) ? feat1 : feat2;
    const float* wT = (y == 0 || y == 2) ? wTt11 : wTt22;
    const float* bias = (y == 0 || y == 2) ? b11 : b22;
    float* outp = y == 0 ? f1 : y == 1 ? f2 : y == 2 ? g1 : g2;
    int tid = threadIdx.x;
    int n0 = blockIdx.x * 64;
    int b = n0 >> 12, nloc = n0 & 4095;
    const float* xb = x + (size_t)b * 64 * NPTS + nloc;
    #pragma unroll
    for (int i = 0; i < 16; ++i) {
        int e = tid + 256 * i;
        int ci = e >> 6, nn = e & 63;
        xs[ci][nn] = xb[(size_t)ci * NPTS + nn];
    }
    __syncthreads();
    int co = (tid & 31) * 4;
    int r0 = (tid >> 5) * 8;
    float acc[4][8];
    float4 bv = *(const float4*)&bias[co];
    #pragma unroll
    for (int j = 0; j < 8; ++j) { acc[0][j] = bv.x; acc[1][j] = bv.y; acc[2][j] = bv.z; acc[3][j] = bv.w; }
    for (int ci = 0; ci < 64; ++ci) {
        float4 wv = *(const float4*)&wT[(size_t)ci * CC + co];
        #pragma unroll
        for (int j = 0; j < 8; ++j) {
            float xv = xs[ci][r0 + j];
            acc[0][j] += wv.x * xv;
            acc[1][j] += wv.y * xv;
            acc[2][j] += wv.z * xv;
            acc[3][j] += wv.w * xv;
        }
    }
    #pragma unroll
    for (int j = 0; j < 8; ++j) {
        *(float4*)&outp[(size_t)(n0 + r0 + j) * CC + co] =
            make_float4(acc[0][j], acc[1][j], acc[2][j], acc[3][j]);
    }
}

// ---------------------------------------------------------------- 64-bit shuffles
static __device__ __forceinline__ unsigned long long sxor64(unsigned long long v, int m) {
    unsigned lo = (unsigned)__shfl_xor((int)(unsigned)v, m);
    unsigned hi = (unsigned)__shfl_xor((int)(v >> 32), m);
    return ((unsigned long long)hi << 32) | lo;
}

// ------------------------------------------------- KNN: atomic-append pass 2
__global__ __launch_bounds__(512) void knn_kernel(
        const float* __restrict__ pc1, const float* __restrict__ pc2,
        int* __restrict__ idx12, int* __restrict__ idx21) {
#pragma clang fp contract(off)
    __shared__ float4 pk[NPTS];                           // 64 KB
    __shared__ unsigned long long lst[8][4][63];          // 15.75 KB
    __shared__ int cnt[8][4];                             // 128 B
    int dir = blockIdx.y;
    const float* qs = dir ? pc2 : pc1;
    const float* cs = dir ? pc1 : pc2;
    int* outIdx = dir ? idx21 : idx12;
    int tid = threadIdx.x, lane = tid & 63, wv = tid >> 6;
    int qbase = blockIdx.x * 32;
    int b = qbase >> 12;
    const float* cb = cs + (size_t)b * 3 * NPTS;
    for (int i = tid; i < NPTS; i += 512) {
        float x = cb[i], y = cb[NPTS + i], z = cb[2 * NPTS + i];
        pk[i] = make_float4(x, y, z, x * x + y * y + z * z);  // l2r, no fma
    }
    __syncthreads();
    const float* qb = qs + (size_t)b * 3 * NPTS;
    int q0 = qbase + wv * 4;
    float qx[4], qy[4], qz[4], s1[4], dmin[4], T[4];
    #pragma unroll
    for (int t = 0; t < 4; ++t) {
        int n = (q0 + t) & 4095;
        qx[t] = qb[n]; qy[t] = qb[NPTS + n]; qz[t] = qb[2 * NPTS + n];
        s1[t] = qx[t] * qx[t] + qy[t] * qy[t] + qz[t] * qz[t];
        dmin[t] = 1e30f;
    }
    for (int j = 0; j < 64; ++j) {
        float4 P = pk[j * 64 + lane];
        #pragma unroll
        for (int t = 0; t < 4; ++t) {
            float dt = __builtin_fmaf(P.z, qz[t], __builtin_fmaf(P.y, qy[t], P.x * qx[t]));
            float d2 = (s1[t] + P.w) - 2.0f * dt;
            dmin[t] = fminf(dmin[t], d2);
        }
    }
    #pragma unroll
    for (int t = 0; t < 4; ++t) {
        float sv = dmin[t];
        for (int k = 2; k <= 64; k <<= 1)
            for (int j = k >> 1; j > 0; j >>= 1) {
                float o = __shfl_xor(sv, j);
                bool tmin = (((lane & k) == 0) == ((lane & j) == 0));
                sv = tmin ? fminf(sv, o) : fmaxf(sv, o);
            }
        T[t] = __shfl(sv, 15);
    }
    if (lane < 4) cnt[wv][lane] = 0;
    for (int j = 0; j < 64; ++j) {
        float4 P = pk[j * 64 + lane];
        int m = j * 64 + lane;
        #pragma unroll
        for (int t = 0; t < 4; ++t) {
            float dt = __builtin_fmaf(P.z, qz[t], __builtin_fmaf(P.y, qy[t], P.x * qx[t]));
            float d2 = (s1[t] + P.w) - 2.0f * dt;
            if (d2 <= T[t]) {
                unsigned u = __float_as_uint(d2);
                u ^= (unsigned)(((int)u >> 31) | 0x80000000);
                int pos = atomicAdd(&cnt[wv][t], 1);
                if (pos < 63) lst[wv][t][pos] = ((unsigned long long)u << 32) | (unsigned)m;
            }
        }
    }
    #pragma unroll
    for (int t = 0; t < 4; ++t) {
        int nT = cnt[wv][t]; if (nT > 63) nT = 63;
        unsigned long long key = (lane < nT) ? lst[wv][t][lane] : ~0ULL;
        for (int k = 2; k <= 64; k <<= 1)
            for (int j = k >> 1; j > 0; j >>= 1) {
                unsigned long long o = sxor64(key, j);
                bool tmin = (((lane & k) == 0) == ((lane & j) == 0));
                unsigned long long mn = key < o ? key : o;
                unsigned long long mx = key < o ? o : key;
                key = tmin ? mn : mx;
            }
        if (lane < KNN) outIdx[(size_t)(q0 + t) * KNN + lane] = (int)(unsigned)(key & 0xFFFFFFFFULL);
    }
}

// ------------------------------------------------- h0 (dual: cross1 / cross2 by blockIdx.y)
__global__ void h0_kernel(const float* p1f_1, const float* p2f_1,
                          const float* p1f_2, const float* p2f_2,
                          const float* __restrict__ pc1, const float* __restrict__ pc2,
                          const int* idx_1, const int* idx_2,
                          const float* __restrict__ pos_w, const float* __restrict__ pos_b,
                          ushort_t* buf_1, ushort_t* buf_2,
                          float* stats_1, float* stats_2) {
    __shared__ float redS[128], redQ[128];
    int y = blockIdx.y;
    const float* p1f = y ? p1f_2 : p1f_1;
    const float* p2f = y ? p2f_2 : p2f_1;
    const float* pcA = y ? pc2 : pc1;
    const float* pcB = y ? pc1 : pc2;
    const int* idx = y ? idx_2 : idx_1;
    ushort_t* buf = y ? buf_2 : buf_1;
    float* stats_out = y ? stats_2 : stats_1;
    int p = blockIdx.x;                    // b*N + n
    int b = p >> 12, n = p & 4095;
    int c = threadIdx.x;
    float pw0 = pos_w[c * 3], pw1 = pos_w[c * 3 + 1], pw2 = pos_w[c * 3 + 2];
    float pb = pos_b[c];
    float p1v = p1f[(size_t)p * CC + c];
    const float* pa = pcA + (size_t)b * 3 * NPTS;
    const float* pc = pcB + (size_t)b * 3 * NPTS;
    float qx = pa[n], qy = pa[NPTS + n], qz = pa[2 * NPTS + n];
    float S = 0.f, Q = 0.f;
    for (int k = 0; k < KNN; ++k) {
        int m = idx[(size_t)p * KNN + k];
        float dx = pc[m] - qx;
        float dy = pc[NPTS + m] - qy;
        float dz = pc[2 * NPTS + m] - qz;
        float pos = pw0 * dx + pw1 * dy + pw2 * dz + pb;
        float v = p2f[((size_t)b * NPTS + m) * CC + c] + p1v + pos;
        buf[((size_t)p * KNN + k) * CC + c] = f2bf(v);
        S += v; Q += v * v;
    }
    redS[c] = S; redQ[c] = Q;
    __syncthreads();
    if (c < 8) {
        float SS = 0.f, QQ = 0.f;
        for (int i = 0; i < 16; ++i) { SS += redS[c * 16 + i]; QQ += redQ[c * 16 + i]; }
        int s = blockIdx.x & 31;
        atomicAdd(&stats_out[s * 32 + (b * 8 + c) * 2],     SS);
        atomicAdd(&stats_out[s * 32 + (b * 8 + c) * 2 + 1], QQ);
    }
}

// ------------------------------------------------- convgn (dual): exact R12 structure —
// 64-row tile, cooperative staging burst, MFMA from LDS, wave-private output slab,
// LDS stats merge + final barrier + 16 atomics/block. Proven 53 us.
__global__ __launch_bounds__(256) void convgn_kernel(
        const ushort_t* xbuf_1, const ushort_t* xbuf_2,
        const float* stats_in_1, const float* stats_in_2,
        const float* __restrict__ gam, const float* __restrict__ bet,
        const ushort_t* __restrict__ W2, const float* __restrict__ bias,
        ushort_t* ybuf_1, ushort_t* ybuf_2,
        float* stats_out_1, float* stats_out_2) {
    __shared__ ushort_t xt[64 * 136];
    __shared__ float sc[CC], sh[CC];
    __shared__ float redS[4][8], redQ[4][8];
    int y = blockIdx.y;
    const ushort_t* xbuf = y ? xbuf_2 : xbuf_1;
    const float* stats_in = y ? stats_in_2 : stats_in_1;
    ushort_t* ybuf = y ? ybuf_2 : ybuf_1;
    float* stats_out = y ? stats_out_2 : stats_out_1;
    int tid = threadIdx.x;
    int s0 = blockIdx.x * 64;
    int b = s0 >> 16;
    if (tid < CC) {
        int g = tid >> 4;
        float S = 0.f, Q = 0.f;
        for (int s = 0; s < 32; ++s) {
            S += stats_in[s * 32 + (b * 8 + g) * 2];
            Q += stats_in[s * 32 + (b * 8 + g) * 2 + 1];
        }
        float mu = S / CNT_PER_GROUP;
        float var = Q / CNT_PER_GROUP - mu * mu;
        float rs = rsqrtf(var + 1e-5f);
        float scale = gam[tid] * rs;
        sc[tid] = scale;
        sh[tid] = bet[tid] - mu * scale;
    }
    __syncthreads();
    // cooperative staging: all 256 threads issue 4 independent u16x8 loads (MLP burst)
    #pragma unroll
    for (int j = 0; j < 4; ++j) {
        int idx = tid + 256 * j;
        int row = idx >> 4, c8 = (idx & 15) * 8;
        u16x8 vin = *(const u16x8*)&xbuf[(size_t)(s0 + row) * CC + c8];
        u16x8 vo;
        #pragma unroll
        for (int e = 0; e < 8; ++e) {
            float v = bf2f(vin[e]) * sc[c8 + e] + sh[c8 + e];
            v = v >= 0.f ? v : 0.1f * v;
            vo[e] = f2bf(v);
        }
        *(u16x8*)&xt[row * 136 + c8] = vo;
    }
    __syncthreads();
    int lane = tid & 63, wv = tid >> 6;
    int r0 = wv * 16;
    int quad = lane >> 4, r = lane & 15;
    f32x4 acc[8];
    #pragma unroll
    for (int t = 0; t < 8; ++t) acc[t] = (f32x4){0.f, 0.f, 0.f, 0.f};
    int aoff = (r0 + r) * 136 + quad * 8;
    #pragma unroll
    for (int kb = 0; kb < 4; ++kb) {
        bf16x8 a = *(const bf16x8*)&xt[aoff + kb * 32];
        const ushort_t* wb = W2 + (size_t)kb * 4096 + lane * 8;
        #pragma unroll
        for (int t = 0; t < 8; ++t) {
            bf16x8 bf = *(const bf16x8*)&wb[t * 512];
            acc[t] = __builtin_amdgcn_mfma_f32_16x16x32_bf16(a, bf, acc[t], 0, 0, 0);
        }
    }
    // epilogue: bias + stats; stage bf16 into wave-private slab (rows r0..r0+15)
    #pragma unroll
    for (int t = 0; t < 8; ++t) {
        int co = t * 16 + r;
        float bv = bias[co];
        float S = 0.f, Q = 0.f;
        #pragma unroll
        for (int reg = 0; reg < 4; ++reg) {
            int rl = r0 + quad * 4 + reg;
            float yv = acc[t][reg] + bv;
            xt[rl * 136 + co] = f2bf(yv);
            S += yv; Q += yv * yv;
        }
        #pragma unroll
        for (int off = 1; off < 64; off <<= 1) {
            S += __shfl_xor(S, off);
            Q += __shfl_xor(Q, off);
        }
        if (lane == 0) { redS[wv][t] = S; redQ[wv][t] = Q; }
    }
    // wave-private slab -> coalesced 16B global stores (no barrier: own rows only)
    #pragma unroll
    for (int i = 0; i < 4; ++i) {
        int chunk = i * 64 + lane;             // row(4b) x c8(4b) within wave tile
        int rl = r0 + (chunk >> 4);
        int c8 = (chunk & 15) * 8;
        u16x8 v = *(const u16x8*)&xt[rl * 136 + c8];
        *(u16x8*)&ybuf[(size_t)(s0 + rl) * CC + c8] = v;
    }
    __syncthreads();
    if (tid < 8) {
        float S = redS[0][tid] + redS[1][tid] + redS[2][tid] + redS[3][tid];
        float Q = redQ[0][tid] + redQ[1][tid] + redQ[2][tid] + redQ[3][tid];
        int s = blockIdx.x & 31;
        atomicAdd(&stats_out[s * 32 + (b * 8 + tid) * 2],     S);
        atomicAdd(&stats_out[s * 32 + (b * 8 + tid) * 2 + 1], Q);
    }
}

// ------------------------------------------------- maxpool (cross3 tail), n-run writes
__global__ __launch_bounds__(256) void maxpool_kernel(
        const ushort_t* __restrict__ ybuf, const float* __restrict__ stats,
        const float* __restrict__ gam, const float* __restrict__ bet,
        float* __restrict__ outb) {
    int p0 = blockIdx.x * 16;
    int b = p0 >> 12, n0 = p0 & 4095;
    int tid = threadIdx.x;
    int c = tid & 127, half = tid >> 7;
    int g = c >> 4;
    float S = 0.f, Q = 0.f;
    for (int s = 0; s < 32; ++s) {
        S += stats[s * 32 + (b * 8 + g) * 2];
        Q += stats[s * 32 + (b * 8 + g) * 2 + 1];
    }
    float mu = S / CNT_PER_GROUP;
    float var = Q / CNT_PER_GROUP - mu * mu;
    float rs = rsqrtf(var + 1e-5f);
    float scale = gam[c] * rs;
    float shift = bet[c] - mu * scale;
    float* orow = outb + ((size_t)b * CC + c) * NPTS + n0 + half * 8;
    #pragma unroll
    for (int j = 0; j < 8; ++j) {
        int nl = half * 8 + j;
        float mx = -INFINITY;
        for (int k = 0; k < KNN; ++k) {
            float v = bf2f(ybuf[((size_t)(p0 + nl) * KNN + k) * CC + c]) * scale + shift;
            v = v >= 0.f ? v : 0.1f * v;
            mx = fmaxf(mx, v);
        }
        orow[j] = mx;
    }
}

// ------------------------------------------------- fused maxpool + conv (dual)
__global__ __launch_bounds__(256) void maxconv_kernel(
        const ushort_t* ybuf_1, const ushort_t* ybuf_2,
        const float* stats_1, const float* stats_2,
        const float* __restrict__ gam, const float* __restrict__ bet,
        const float* wT_1, const float* wT_2,
        const float* bias_1, const float* bias_2,
        float* outf_1, float* outf_2,
        float* __restrict__ outb) {
    __shared__ float mxs[16][CC + 4];
    int y = blockIdx.y;
    const ushort_t* ybuf = y ? ybuf_2 : ybuf_1;
    const float* stats = y ? stats_2 : stats_1;
    const float* wT = y ? wT_2 : wT_1;
    const float* bias = y ? bias_2 : bias_1;
    float* outf = y ? outf_2 : outf_1;
    float* ob = outb + (size_t)y * 2 * NPTS * CC;
    int p0 = blockIdx.x * 16;
    int b = p0 >> 12, n0 = p0 & 4095;
    int tid = threadIdx.x;
    int c = tid & 127, half = tid >> 7;
    int g = c >> 4;
    float S = 0.f, Q = 0.f;
    for (int s = 0; s < 32; ++s) {
        S += stats[s * 32 + (b * 8 + g) * 2];
        Q += stats[s * 32 + (b * 8 + g) * 2 + 1];
    }
    float mu = S / CNT_PER_GROUP;
    float var = Q / CNT_PER_GROUP - mu * mu;
    float rs = rsqrtf(var + 1e-5f);
    float scale = gam[c] * rs;
    float shift = bet[c] - mu * scale;
    #pragma unroll
    for (int j = 0; j < 8; ++j) {
        int nl = half * 8 + j;
        float mx = -INFINITY;
        for (int k = 0; k < KNN; ++k) {
            float v = bf2f(ybuf[((size_t)(p0 + nl) * KNN + k) * CC + c]) * scale + shift;
            v = v >= 0.f ? v : 0.1f * v;
            mx = fmaxf(mx, v);
        }
        mxs[nl][c] = mx;
    }
    __syncthreads();
    float acc[8];
    float bv = bias[c];
    #pragma unroll
    for (int j = 0; j < 8; ++j) acc[j] = bv;
    for (int ci = 0; ci < CC; ++ci) {
        float wv = wT[(size_t)ci * CC + c];
        #pragma unroll
        for (int j = 0; j < 8; ++j)
            acc[j] += wv * mxs[half * 8 + j][ci];
    }
    #pragma unroll
    for (int j = 0; j < 8; ++j)
        outf[(size_t)(p0 + half * 8 + j) * CC + c] = acc[j];
    float* orow = ob + ((size_t)b * CC + c) * NPTS + n0 + half * 8;
    #pragma unroll
    for (int j = 0; j < 8; ++j) orow[j] = acc[j];
}

extern "C" void kernel_launch(void* const* d_in, const int* in_sizes, int n_in,
                              void* d_out, int out_size, void* d_ws, size_t ws_size,
                              hipStream_t stream) {
    (void)in_sizes; (void)n_in; (void)out_size; (void)ws_size;
    const float* pc1    = (const float*)d_in[0];
    const float* pc2    = (const float*)d_in[1];
    const float* feat1  = (const float*)d_in[2];
    const float* feat2  = (const float*)d_in[3];
    const float* t11_w  = (const float*)d_in[4];
    const float* t11_b  = (const float*)d_in[5];
    const float* t22_w  = (const float*)d_in[6];
    const float* t22_b  = (const float*)d_in[7];
    const float* pos1_w = (const float*)d_in[8];
    const float* pos1_b = (const float*)d_in[9];
    const float* gn1_g  = (const float*)d_in[10];
    const float* gn1_b  = (const float*)d_in[11];
    const float* m1a_w  = (const float*)d_in[12];
    const float* m1a_b  = (const float*)d_in[13];
    const float* m1a_g  = (const float*)d_in[14];
    const float* m1a_be = (const float*)d_in[15];
    const float* m1b_w  = (const float*)d_in[16];
    const float* m1b_b  = (const float*)d_in[17];
    const float* m1b_g  = (const float*)d_in[18];
    const float* m1b_be = (const float*)d_in[19];
    const float* t1_w   = (const float*)d_in[20];
    const float* t1_b   = (const float*)d_in[21];
    const float* t2_w   = (const float*)d_in[22];
    const float* t2_b   = (const float*)d_in[23];
    const float* pos2_w = (const float*)d_in[24];
    const float* pos2_b = (const float*)d_in[25];
    const float* gn2_g  = (const float*)d_in[26];
    const float* gn2_b  = (const float*)d_in[27];
    const float* m2a_w  = (const float*)d_in[28];
    const float* m2a_b  = (const float*)d_in[29];
    const float* m2a_g  = (const float*)d_in[30];
    const float* m2a_be = (const float*)d_in[31];

    float* out = (float*)d_out;
    const size_t PN = 2 * NPTS;              // 8192 points
    const size_t PT = PN * CC;               // 1,048,576 elements per point-tensor
    float* ws   = (float*)d_ws;
    float* f1   = ws;
    float* f2   = f1 + PT;
    float* g1   = f2 + PT;
    float* g2   = g1 + PT;
    float* f1n  = g2 + PT;
    float* f2n  = f1n + PT;
    int*   idx12 = (int*)(f2n + PT);
    int*   idx21 = idx12 + PN * KNN;
    float* stats = (float*)(idx21 + PN * KNN);     // 8 stages * 1024
    float* wTt11 = stats + 8 * STAT_STRIDE;
    float* wTt22 = wTt11 + 64 * CC;
    float* wTt1  = wTt22 + 64 * CC;
    float* wTt2  = wTt1 + CC * CC;
    ushort_t* W2m1a = (ushort_t*)(wTt2 + CC * CC);
    ushort_t* W2m1b = W2m1a + 16384;
    ushort_t* W2m2a = W2m1b + 16384;
    ushort_t* bufX1 = W2m2a + 16384;               // bf16 [PN*KNN*CC] each
    ushort_t* bufY1 = bufX1 + (size_t)PN * KNN * CC;
    ushort_t* bufX2 = bufY1 + (size_t)PN * KNN * CC;
    ushort_t* bufY2 = bufX2 + (size_t)PN * KNN * CC;

    prep_kernel<<<dim3(64, 8), 256, 0, stream>>>(
        t11_w, t22_w, t1_w, t2_w, m1a_w, m1b_w, m2a_w,
        wTt11, wTt22, wTt1, wTt2, W2m1a, W2m1b, W2m2a, stats);

    conv64_kernel<<<dim3(PN / 64, 4), 256, 0, stream>>>(
        feat1, feat2, wTt11, wTt22, t11_b, t22_b, f1, f2, g1, g2);
    knn_kernel<<<dim3(PN / 32, 2), 512, 0, stream>>>(pc1, pc2, idx12, idx21);

    float* st0 = stats;
    // ---- cross1 + cross2 merged (independent pipelines, blockIdx.y selects)
    h0_kernel<<<dim3(PN, 2), 128, 0, stream>>>(
        f1, f2, g1, g2, pc1, pc2, idx12, idx21, pos1_w, pos1_b,
        bufX1, bufX2, st0 + 0 * STAT_STRIDE, st0 + 3 * STAT_STRIDE);
    convgn_kernel<<<dim3(2048, 2), 256, 0, stream>>>(
        bufX1, bufX2, st0 + 0 * STAT_STRIDE, st0 + 3 * STAT_STRIDE,
        gn1_g, gn1_b, W2m1a, m1a_b,
        bufY1, bufY2, st0 + 1 * STAT_STRIDE, st0 + 4 * STAT_STRIDE);
    convgn_kernel<<<dim3(2048, 2), 256, 0, stream>>>(
        bufY1, bufY2, st0 + 1 * STAT_STRIDE, st0 + 4 * STAT_STRIDE,
        m1a_g, m1a_be, W2m1b, m1b_b,
        bufX1, bufX2, st0 + 2 * STAT_STRIDE, st0 + 5 * STAT_STRIDE);
    maxconv_kernel<<<dim3(PN / 16, 2), 256, 0, stream>>>(
        bufX1, bufX2, st0 + 2 * STAT_STRIDE, st0 + 5 * STAT_STRIDE,
        m1b_g, m1b_be, wTt1, wTt2, t1_b, t2_b, f1n, f2n, out);

    // ---- cross3: (pc1, pc2, feat1_new, feat2_new) -> feat1_final
    h0_kernel<<<dim3(PN, 1), 128, 0, stream>>>(
        f1n, f2n, f1n, f2n, pc1, pc2, idx12, idx12, pos2_w, pos2_b,
        bufX1, bufX1, st0 + 6 * STAT_STRIDE, st0 + 6 * STAT_STRIDE);
    convgn_kernel<<<dim3(2048, 1), 256, 0, stream>>>(
        bufX1, bufX1, st0 + 6 * STAT_STRIDE, st0 + 6 * STAT_STRIDE,
        gn2_g, gn2_b, W2m2a, m2a_b,
        bufY1, bufY1, st0 + 7 * STAT_STRIDE, st0 + 7 * STAT_STRIDE);
    maxpool_kernel<<<PN / 16, 256, 0, stream>>>(
        bufY1, st0 + 7 * STAT_STRIDE, m2a_g, m2a_be, out + 2 * PT);
}